// Round 12
// baseline (769.150 us; speedup 1.0000x reference)
//
#include <hip/hip_runtime.h>
#include <hip/hip_bf16.h>
#include <hip/hip_cooperative_groups.h>

namespace cg = cooperative_groups;

// SE3EncoderDecoderQM9: B=16,N=128,H=4,DH=16,C=64,NRBF=16,L=2, R=10
// SINGLE cooperative kernel: conv+table | proj0 | attn0 | post+ff+proj1 |
// attn1 | post+ff | final, separated by grid.sync(). Eliminates 6 kernel
// boundaries (L2 flush + barrier packets) diagnosed as the ~120us floor.

typedef __hip_bfloat16 bf16;
typedef __attribute__((ext_vector_type(8))) short short8;
typedef __attribute__((ext_vector_type(4))) float float4v;

__device__ __forceinline__ float waveSum64(float v) {
#pragma unroll
  for (int m = 1; m < 64; m <<= 1) v += __shfl_xor(v, m, 64);
  return v;
}
__device__ __forceinline__ float bits2f(unsigned short b) {
  return __uint_as_float(((unsigned int)b) << 16);
}
__device__ __forceinline__ unsigned short f2bu(float f) {
  unsigned int u = __float_as_uint(f);
  u = (u + 0x7fffu + ((u >> 16) & 1u)) >> 16;  // RNE
  return (unsigned short)u;
}
__device__ __forceinline__ short8 pack8(float4 a, float4 b) {
  short8 r;
  r[0] = (short)f2bu(a.x); r[1] = (short)f2bu(a.y);
  r[2] = (short)f2bu(a.z); r[3] = (short)f2bu(a.w);
  r[4] = (short)f2bu(b.x); r[5] = (short)f2bu(b.y);
  r[6] = (short)f2bu(b.z); r[7] = (short)f2bu(b.w);
  return r;
}
__device__ __forceinline__ int voteSlice(const unsigned short* u, int start, int stride) {
  int insane = 0;
  for (int e = start; e < 1024; e += stride) {
    float f = bits2f(u[2 * e]);
    float af = fabsf(f);
    insane += (!(af < 1e4f) || (f != 0.f && af < 1e-20f)) ? 1 : 0;
  }
  return insane;
}
__device__ __forceinline__ float ldraw(const void* src, int idx, bool isbf) {
  if (isbf) return bits2f(((const unsigned short*)src)[idx]);
  return ((const float*)src)[idx];
}

struct ConvArgs {
  const void* src[30];
  int off[31];
};

// ---- shared-memory union across phases (38.4 KB, 4 blocks/CU) ----
union MegaU {
  struct {                              // attention phase
    unsigned short UU[8192];            // ks[128][64] aliased A16[64][128]
    unsigned int SS[1024];              // S01[8][128]
    unsigned short BT[8192];            // Bt[64][128]
    float CS[384];                      // cs[3][128]
  } a;
  struct {                              // node (post+ff+proj) phase
    float pp[4][12][64];
    float o0s[64], rs[64], xnl[64], hb[256];
    float o1s[192], f1g[192], f1n[192], x0s[64];
  } n;
  struct { float sW1[512], sb1[32], sW2[512], sb2[16]; } t;  // table phase
  struct { float fs[2][12], x0[2][64]; } p;                  // proj0 phase
  struct { float ps[64]; } f;                                // final phase
};

// ---- attention body (validated r7-r11), unit u = (it<<6)|bh ----
template <int HASF1>
__device__ void att_body(MegaU& M, int u, const float* __restrict__ coords,
                         const float2* __restrict__ tab, const float* __restrict__ q0,
                         const float* __restrict__ k0, const float* __restrict__ v0,
                         const float* __restrict__ q1, const float* __restrict__ k1,
                         const float* __restrict__ v1, float* __restrict__ out0,
                         float* __restrict__ out1, int tid) {
  int bh = u & 63, it = u >> 6;
  int h = bh & 3, b = bh >> 2;
  int ibase = it * 8;
  size_t rowbase = (size_t)bh * 128;
  int lane = tid & 63, waveid = tid >> 6;
  int ln = lane & 15, lg = lane >> 4;

  short8 P0f = {0, 0, 0, 0, 0, 0, 0, 0};
  short8 P1f = {0, 0, 0, 0, 0, 0, 0, 0};
  short8 P2f = {0, 0, 0, 0, 0, 0, 0, 0};
  if (ln < 8) {
    int i = ibase + ln;
    if (HASF1) {
      const float* q1p = q1 + (rowbase + i) * 48;
      float4 fa = *(const float4*)&q1p[lg * 8];
      float4 fb = *(const float4*)&q1p[lg * 8 + 4];
      P0f = pack8(fa, fb);
      if (lg < 2) {
        fa = *(const float4*)&q1p[32 + lg * 8];
        fb = *(const float4*)&q1p[32 + lg * 8 + 4];
        P1f = pack8(fa, fb);
      }
    }
    if (lg >= 2) {
      const float* q0p = q0 + (rowbase + i) * 16;
      float4 fa = *(const float4*)&q0p[(lg - 2) * 8];
      float4 fb = *(const float4*)&q0p[(lg - 2) * 8 + 4];
      P2f = pack8(fa, fb);
    }
  }

  if (HASF1) {
    for (int e = tid; e < 2048; e += 256) {
      int j = e >> 4, t0 = (e & 15) * 4;
      float4 f;
      if (t0 < 48) f = *(const float4*)&k1[(rowbase + j) * 48 + t0];
      else f = *(const float4*)&k0[(rowbase + j) * 16 + (t0 - 48)];
      int g = t0 >> 3;
      ushort4 pk = {f2bu(f.x), f2bu(f.y), f2bu(f.z), f2bu(f.w)};
      *(ushort4*)&M.a.UU[j * 64 + ((((g ^ (j & 7)) << 3) | (t0 & 7)))] = pk;
    }
  } else {
    for (int e = tid; e < 1024; e += 256) {
      int j = e >> 3, t0 = 32 + (e & 7) * 4;
      ushort4 pk = {0, 0, 0, 0};
      if (t0 >= 48) {
        float4 f = *(const float4*)&k0[(rowbase + j) * 16 + (t0 - 48)];
        pk.x = f2bu(f.x); pk.y = f2bu(f.y); pk.z = f2bu(f.z); pk.w = f2bu(f.w);
      }
      int g = t0 >> 3;
      *(ushort4*)&M.a.UU[j * 64 + ((((g ^ (j & 7)) << 3) | (t0 & 7)))] = pk;
    }
  }
  for (int e = tid; e < 512; e += 256) {
    int j = e >> 2, q = e & 3;
    float4 f = *(const float4*)&v0[(rowbase + j) * 16 + q * 4];
    int jhi = j >> 3, jl = j & 7;
#pragma unroll
    for (int i2 = 0; i2 < 4; ++i2) {
      int d = q * 4 + i2;
      int sl = (jhi ^ d) << 3;
      float fv = (i2 == 0) ? f.x : (i2 == 1) ? f.y : (i2 == 2) ? f.z : f.w;
      M.a.BT[d * 128 + (sl | jl)] = f2bu(fv);
      if (!HASF1) {
        M.a.BT[(16 + d) * 128 + (sl | jl)] = 0;
        M.a.BT[(32 + d) * 128 + (sl | jl)] = 0;
        M.a.BT[(48 + d) * 128 + (sl | jl)] = 0;
      }
    }
  }
  if (HASF1) {
    for (int e = tid; e < 1536; e += 256) {
      int j = e / 12, q = e - j * 12;
      float4 f = *(const float4*)&v1[(rowbase + j) * 48 + q * 4];
      int jhi = j >> 3, jl = j & 7;
#pragma unroll
      for (int i2 = 0; i2 < 4; ++i2) {
        int flat = q * 4 + i2;
        int d = flat / 3, vv = flat - d * 3;
        int sl = (jhi ^ d) << 3;
        float fv = (i2 == 0) ? f.x : (i2 == 1) ? f.y : (i2 == 2) ? f.z : f.w;
        M.a.BT[((vv + 1) * 16 + d) * 128 + (sl | jl)] = f2bu(fv);
      }
    }
  }
  if (tid < 128) {
    M.a.CS[0 * 128 + tid] = coords[((size_t)b * 128 + tid) * 3 + 0];
    M.a.CS[1 * 128 + tid] = coords[((size_t)b * 128 + tid) * 3 + 1];
    M.a.CS[2 * 128 + tid] = coords[((size_t)b * 128 + tid) * 3 + 2];
  }
  __syncthreads();  // bar1

#pragma unroll
  for (int q = 0; q < 2; ++q) {
    int j = (waveid * 2 + q) * 16 + ln;
    int swz = j & 7;
    short8 bk1 = *(const short8*)&M.a.UU[j * 64 + (((4 + lg) ^ swz) << 3)];
    float4v a0 = {0.f, 0.f, 0.f, 0.f};
    a0 = __builtin_amdgcn_mfma_f32_16x16x32_bf16(P2f, bk1, a0, 0, 0, 0);
    float4v a1 = {0.f, 0.f, 0.f, 0.f};
    if (HASF1) {
      short8 bk0 = *(const short8*)&M.a.UU[j * 64 + ((lg ^ swz) << 3)];
      a1 = __builtin_amdgcn_mfma_f32_16x16x32_bf16(P0f, bk0, a1, 0, 0, 0);
      a1 = __builtin_amdgcn_mfma_f32_16x16x32_bf16(P1f, bk1, a1, 0, 0, 0);
    }
    if (lg < 2) {
#pragma unroll
      for (int r = 0; r < 4; ++r) {
        unsigned int pk =
            (unsigned int)f2bu(a0[r]) | ((unsigned int)f2bu(a1[r]) << 16);
        M.a.SS[(lg * 4 + r) * 128 + j] = pk;
      }
    }
  }
  __syncthreads();  // bar2

  {
    int row = tid >> 5, jg = tid & 31;
    int i = ibase + row;
    float cix = M.a.CS[i], ciy = M.a.CS[128 + i], ciz = M.a.CS[256 + i];
    uint4 sv = *(const uint4*)&M.a.SS[row * 128 + jg * 4];
    float e4[4], w4[4][4], yv[4][3];
    int nmmask = 0;
    float mx = -3e38f;
#pragma unroll
    for (int jj = 0; jj < 4; ++jj) {
      int j = jg * 4 + jj;
      float rx = M.a.CS[j] - cix;
      float ry = M.a.CS[128 + j] - ciy;
      float rz = M.a.CS[256 + j] - ciz;
      float dd = sqrtf(rx * rx + ry * ry + rz * rz + 1e-8f);
      float inv = 1.f / dd;
      yv[jj][0] = rx * inv; yv[jj][1] = ry * inv; yv[jj][2] = rz * inv;
      float tt = fminf(dd, 10.229f) * 100.f;
      int i0 = (int)tt;
      float fr = tt - (float)i0;
      const float2* Tp = tab + (i0 << 4) + h;
      float2 t0 = Tp[0], t1 = Tp[4], t2 = Tp[8], t3 = Tp[12];
      w4[jj][0] = t0.x + fr * (t0.y - t0.x);
      w4[jj][1] = t1.x + fr * (t1.y - t1.x);
      w4[jj][2] = t2.x + fr * (t2.y - t2.x);
      w4[jj][3] = t3.x + fr * (t3.y - t3.x);
      unsigned int sw = (jj == 0) ? sv.x : (jj == 1) ? sv.y : (jj == 2) ? sv.z : sv.w;
      float s0j = bits2f((unsigned short)(sw & 0xffffu));
      float s1j = bits2f((unsigned short)(sw >> 16));
      float sim = (s0j * w4[jj][0] + (HASF1 ? s1j * w4[jj][3] : 0.f)) * 0.25f;
      bool nm = (dd <= 10.0f) && (j != i);
      if (nm) nmmask |= (1 << jj);
      sim = nm ? sim : -1e9f;
      e4[jj] = sim;
      mx = fmaxf(mx, sim);
    }
#pragma unroll
    for (int m = 1; m < 32; m <<= 1) mx = fmaxf(mx, __shfl_xor(mx, m, 64));
    float ssum = 0.f;
#pragma unroll
    for (int jj = 0; jj < 4; ++jj) {
      e4[jj] = __expf(e4[jj] - mx);
      ssum += e4[jj];
    }
#pragma unroll
    for (int m = 1; m < 32; m <<= 1) ssum += __shfl_xor(ssum, m, 64);
    float rinv = 1.f / ssum;
    float aj[4];
#pragma unroll
    for (int jj = 0; jj < 4; ++jj)
      aj[jj] = ((nmmask >> jj) & 1) ? e4[jj] * rinv : 0.f;
#pragma unroll
    for (int s = 0; s < 8; ++s) {
      unsigned short t4[4];
#pragma unroll
      for (int jj = 0; jj < 4; ++jj) {
        float v;
        if (s == 0) v = aj[jj] * w4[jj][0];
        else if (s < 4) v = aj[jj] * w4[jj][2] * yv[jj][s - 1];
        else if (s < 7) v = aj[jj] * w4[jj][1] * yv[jj][s - 4];
        else v = aj[jj] * w4[jj][3];
        t4[jj] = f2bu(v);
      }
      ushort4 pk = {t4[0], t4[1], t4[2], t4[3]};
      int arow = row * 8 + s;
      int g = jg >> 1;
      *(ushort4*)&M.a.UU[arow * 128 + ((((g ^ (arow & 15)) << 3) | ((jg & 1) * 4)))] = pk;
    }
  }
  __syncthreads();  // bar3

  float4v acc[4];
#pragma unroll
  for (int nt = 0; nt < 4; ++nt) acc[nt] = (float4v){0.f, 0.f, 0.f, 0.f};
  int m = waveid * 16 + ln;
#pragma unroll
  for (int kst = 0; kst < 4; ++kst) {
    int gk = kst * 4 + lg;
    short8 af = *(const short8*)&M.a.UU[m * 128 + ((gk ^ ln) << 3)];
#pragma unroll
    for (int nt = 0; nt < 4; ++nt) {
      short8 bf = *(const short8*)&M.a.BT[(nt * 16 + ln) * 128 + ((gk ^ ln) << 3)];
      acc[nt] = __builtin_amdgcn_mfma_f32_16x16x32_bf16(af, bf, acc[nt], 0, 0, 0);
    }
  }
  {
    int qr = waveid * 2 + (lg >> 1);
    size_t orow = rowbase + ibase + qr;
    if ((lg & 1) == 0) {
      out0[orow * 16 + ln] = acc[0][0] + acc[1][1] + acc[2][2] + acc[3][3];
    } else {
#pragma unroll
      for (int vv = 0; vv < 3; ++vv)
        out1[orow * 48 + ln * 3 + vv] = acc[0][vv] + acc[1 + vv][3];
    }
  }
  __syncthreads();  // protect LDS reuse
}

// ---- node body (validated r9): post + FF (+ next proj), one row ----
template <int LAST>
__device__ void node_body(MegaU& M, int row, const float* __restrict__ Wo0,
                          const float* __restrict__ bo0, const float* __restrict__ Wo1,
                          const float* __restrict__ gn, const float* __restrict__ bn,
                          const float* __restrict__ g2, const float* __restrict__ b2w,
                          const float* __restrict__ F1, const float* __restrict__ fb1,
                          const float* __restrict__ F2, const float* __restrict__ fb2,
                          const float* __restrict__ Wf1, const float* __restrict__ g0n,
                          const float* __restrict__ b0n, const float* __restrict__ Wq0n,
                          const float* __restrict__ Wk0n, const float* __restrict__ Wv0n,
                          const float* __restrict__ Wq1n, const float* __restrict__ Wk1n,
                          const float* __restrict__ Wv1n, const float* __restrict__ out0,
                          const float* __restrict__ out1, float* __restrict__ f0,
                          float* __restrict__ q0, float* __restrict__ k0,
                          float* __restrict__ v0, float* __restrict__ q1,
                          float* __restrict__ k1, float* __restrict__ v1, int tid) {
  int g = tid >> 6, c = tid & 63;
  int b = row >> 7, n = row & 127;

  if (tid < 64) {
    int h = tid >> 4, d = tid & 15;
    M.n.o0s[tid] = out0[((size_t)((b * 4 + h) * 128 + n)) * 16 + d];
  } else if (!LAST) {
    int t = tid - 64;
    int cc = t / 3, v = t - cc * 3;
    int h = cc >> 4, d = cc & 15;
    M.n.o1s[t] = out1[((size_t)((b * 4 + h) * 128 + n)) * 48 + d * 3 + v];
  }
  __syncthreads();
  {
    float a0 = 0, ax = 0, ay = 0, az = 0;
#pragma unroll
    for (int mi = 0; mi < 16; ++mi) {
      int m = g * 16 + mi;
      a0 += M.n.o0s[m] * Wo0[m * 64 + c];
      if (!LAST) {
        float w = Wo1[m * 64 + c];
        ax += M.n.o1s[m * 3 + 0] * w;
        ay += M.n.o1s[m * 3 + 1] * w;
        az += M.n.o1s[m * 3 + 2] * w;
      }
    }
    M.n.pp[g][0][c] = a0;
    if (!LAST) { M.n.pp[g][1][c] = ax; M.n.pp[g][2][c] = ay; M.n.pp[g][3][c] = az; }
  }
  __syncthreads();
  if (tid < 64) {
    float a0 = bo0[c] + M.n.pp[0][0][c] + M.n.pp[1][0][c] + M.n.pp[2][0][c] + M.n.pp[3][0][c];
    float f0p = f0[(size_t)row * 64 + c] + a0;
    M.n.rs[c] = f0p;
    if (!LAST) {
      float fx = M.n.pp[0][1][c] + M.n.pp[1][1][c] + M.n.pp[2][1][c] + M.n.pp[3][1][c];
      float fy = M.n.pp[0][2][c] + M.n.pp[1][2][c] + M.n.pp[2][2][c] + M.n.pp[3][2][c];
      float fz = M.n.pp[0][3][c] + M.n.pp[1][3][c] + M.n.pp[2][3][c] + M.n.pp[3][3][c];
      float n1 = sqrtf(fx * fx + fy * fy + fz * fz + 1e-8f);
      float gate = fmaxf(n1 * gn[c] + bn[c], 0.f);
      float sc = gate / n1;
      M.n.f1g[c * 3 + 0] = fx * sc;
      M.n.f1g[c * 3 + 1] = fy * sc;
      M.n.f1g[c * 3 + 2] = fz * sc;
    }
    float mu = waveSum64(f0p) * (1.f / 64.f);
    float dv = f0p - mu;
    float var = waveSum64(dv * dv) * (1.f / 64.f);
    M.n.xnl[c] = dv * rsqrtf(var + 1e-5f) * g2[c] + b2w[c];
  }
  __syncthreads();
  {
    float a = fb1[tid];
    for (int cc = 0; cc < 64; ++cc) a += M.n.xnl[cc] * F1[cc * 256 + tid];
    M.n.hb[tid] = fmaxf(a, 0.f);
  }
  __syncthreads();
  {
    float s = 0;
#pragma unroll 8
    for (int kk = 0; kk < 64; ++kk) {
      int k = g * 64 + kk;
      s += M.n.hb[k] * F2[k * 64 + c];
    }
    M.n.pp[g][4][c] = s;
    if (!LAST) {
      float sx = 0, sy = 0, sz = 0;
#pragma unroll
      for (int mi = 0; mi < 16; ++mi) {
        int m = g * 16 + mi;
        float w = Wf1[m * 64 + c];
        sx += M.n.f1g[m * 3 + 0] * w;
        sy += M.n.f1g[m * 3 + 1] * w;
        sz += M.n.f1g[m * 3 + 2] * w;
      }
      M.n.pp[g][5][c] = sx; M.n.pp[g][6][c] = sy; M.n.pp[g][7][c] = sz;
    }
  }
  __syncthreads();
  if (tid < 64) {
    float f0n = M.n.rs[c] + fb2[c] + M.n.pp[0][4][c] + M.n.pp[1][4][c] + M.n.pp[2][4][c] +
                M.n.pp[3][4][c];
    f0[(size_t)row * 64 + c] = f0n;
    if (!LAST) {
      M.n.f1n[c * 3 + 0] =
          M.n.f1g[c * 3 + 0] + M.n.pp[0][5][c] + M.n.pp[1][5][c] + M.n.pp[2][5][c] + M.n.pp[3][5][c];
      M.n.f1n[c * 3 + 1] =
          M.n.f1g[c * 3 + 1] + M.n.pp[0][6][c] + M.n.pp[1][6][c] + M.n.pp[2][6][c] + M.n.pp[3][6][c];
      M.n.f1n[c * 3 + 2] =
          M.n.f1g[c * 3 + 2] + M.n.pp[0][7][c] + M.n.pp[1][7][c] + M.n.pp[2][7][c] + M.n.pp[3][7][c];
      float mu2 = waveSum64(f0n) * (1.f / 64.f);
      float dv2 = f0n - mu2;
      float var2 = waveSum64(dv2 * dv2) * (1.f / 64.f);
      M.n.x0s[c] = dv2 * rsqrtf(var2 + 1e-5f) * g0n[c] + b0n[c];
    }
  }
  __syncthreads();
  if (!LAST) {
    {
      float q[12];
#pragma unroll
      for (int j = 0; j < 12; ++j) q[j] = 0.f;
#pragma unroll
      for (int t = 0; t < 16; ++t) {
        int cc = g * 16 + t;
        float x = M.n.x0s[cc];
        float fx = M.n.f1n[cc * 3 + 0], fy = M.n.f1n[cc * 3 + 1], fz = M.n.f1n[cc * 3 + 2];
        q[0] += x * Wq0n[cc * 64 + c];
        q[1] += x * Wk0n[cc * 64 + c];
        q[2] += x * Wv0n[cc * 64 + c];
        float w = Wq1n[cc * 64 + c];
        q[3] += fx * w; q[4] += fy * w; q[5] += fz * w;
        w = Wk1n[cc * 64 + c];
        q[6] += fx * w; q[7] += fy * w; q[8] += fz * w;
        w = Wv1n[cc * 64 + c];
        q[9] += fx * w; q[10] += fy * w; q[11] += fz * w;
      }
#pragma unroll
      for (int j = 0; j < 12; ++j) M.n.pp[g][j][c] = q[j];
    }
    __syncthreads();
    if (tid < 64) {
      int h = c >> 4, d = c & 15;
      size_t rb = (size_t)((b * 4 + h) * 128 + n);
      float rr[12];
#pragma unroll
      for (int j = 0; j < 12; ++j)
        rr[j] = M.n.pp[0][j][c] + M.n.pp[1][j][c] + M.n.pp[2][j][c] + M.n.pp[3][j][c];
      size_t o0 = rb * 16 + d;
      size_t o1 = rb * 48 + d * 3;
      q0[o0] = rr[0]; k0[o0] = rr[1]; v0[o0] = rr[2];
      q1[o1 + 0] = rr[3]; q1[o1 + 1] = rr[4]; q1[o1 + 2] = rr[5];
      k1[o1 + 0] = rr[6]; k1[o1 + 1] = rr[7]; k1[o1 + 2] = rr[8];
      v1[o1 + 0] = rr[9]; v1[o1 + 1] = rr[10]; v1[o1 + 2] = rr[11];
    }
  }
  __syncthreads();
}

// ---- the mega kernel ----
__global__ void __launch_bounds__(256, 4) k_mega(
    ConvArgs ca, float* __restrict__ conv, float2* __restrict__ tab,
    float* __restrict__ f0, float* __restrict__ q0, float* __restrict__ k0,
    float* __restrict__ v0, float* __restrict__ q1, float* __restrict__ k1,
    float* __restrict__ v1, float* __restrict__ out0, float* __restrict__ out1,
    void* __restrict__ dout) {
  __shared__ MegaU M;
  __shared__ int cnt;
  cg::grid_group grid = cg::this_grid();
  int tid = threadIdx.x;
  int bid = blockIdx.x;
  int G = gridDim.x;
  const int TOTAL = 173619, NCONV = 679;

  // dtype vote (once, per block)
  if (tid == 0) cnt = 0;
  __syncthreads();
  atomicAdd(&cnt, voteSlice((const unsigned short*)ca.src[0], tid, 256));
  __syncthreads();
  bool isbf = (cnt <= 100);
  __syncthreads();

  // ---- P0: convert + table ----
  for (int w = bid; w < NCONV + 8; w += G) {
    if (w < NCONV) {
      int e = w * 256 + tid;
      if (e < TOTAL) {
        int k = 0;
        while (k < 29 && ca.off[k + 1] <= e) k++;
        conv[e] = ldraw(ca.src[k], e - ca.off[k], isbf);
      }
    } else {
      int gidx = (w - NCONV) * 256 + tid;
      int l = gidx >> 10, bin = gidx & 1023;
      for (int k = tid; k < 512; k += 256) {
        M.t.sW1[k] = ldraw(ca.src[10], l * 512 + k, isbf);
        M.t.sW2[k] = ldraw(ca.src[12], l * 512 + k, isbf);
      }
      if (tid < 32) M.t.sb1[tid] = ldraw(ca.src[11], l * 32 + tid, isbf);
      if (tid < 16) M.t.sb2[tid] = ldraw(ca.src[13], l * 16 + tid, isbf);
      __syncthreads();
      float w2[2][16];
#pragma unroll
      for (int t = 0; t < 2; ++t) {
        float d = (float)(bin + t) * 0.01f;
        float rbf[16];
#pragma unroll
        for (int r = 0; r < 16; ++r) {
          float x = d - (10.0f / 15.0f) * (float)r;
          rbf[r] = __expf(-x * x * 1.28f);
        }
#pragma unroll
        for (int o = 0; o < 16; ++o) w2[t][o] = M.t.sb2[o];
        for (int k = 0; k < 32; ++k) {
          float acc = M.t.sb1[k];
#pragma unroll
          for (int r = 0; r < 16; ++r) acc += rbf[r] * M.t.sW1[r * 32 + k];
          acc = fmaxf(acc, 0.f);
#pragma unroll
          for (int o = 0; o < 16; ++o) w2[t][o] += acc * M.t.sW2[k * 16 + o];
        }
      }
#pragma unroll
      for (int o = 0; o < 16; ++o)
        tab[l * 16384 + bin * 16 + o] = make_float2(w2[0][o], w2[1][o]);
      __syncthreads();
    }
  }
  grid.sync();

  // weight pointers (compile-time offsets)
  const float* feats = conv + 0;
  const float* coords = conv + 22528;
  const float* W_emb = conv + 28672;
  const float* b_emb = conv + 29376;
  const float* Wq0 = conv + 29440;
  const float* Wk0 = conv + 37632;
  const float* Wv0 = conv + 45824;
  const float* Wq1 = conv + 54016;
  const float* Wk1 = conv + 62208;
  const float* Wv1 = conv + 70400;
  const float* Wo0 = conv + 80736;
  const float* bo0 = conv + 88928;
  const float* Wo1 = conv + 89056;
  const float* g0 = conv + 97248;
  const float* b0 = conv + 97376;
  const float* gn = conv + 97504;
  const float* bn = conv + 97632;
  const float* g2 = conv + 97760;
  const float* b2w = conv + 97888;
  const float* F1 = conv + 98016;
  const float* fb1 = conv + 130784;
  const float* F2 = conv + 131296;
  const float* fb2 = conv + 164064;
  const float* Wf1 = conv + 164192;
  const float* Wout = conv + 172384;
  const float* bout = conv + 173600;

  // ---- P1: proj0 (embed + LN + q0/k0/v0), 2 rows/unit ----
  for (int u = bid; u < 1024; u += G) {
    if (tid < 128) {
      int r = tid >> 6, c = tid & 63;
      int row = u * 2 + r;
      if (c < 11) M.p.fs[r][c] = feats[(size_t)row * 11 + c];
    }
    __syncthreads();
    if (tid < 128) {
      int r = tid >> 6, c = tid & 63;
      int row = u * 2 + r;
      float val = b_emb[c];
#pragma unroll
      for (int k = 0; k < 11; k++) val += M.p.fs[r][k] * W_emb[k * 64 + c];
      f0[(size_t)row * 64 + c] = val;
      float mu = waveSum64(val) * (1.f / 64.f);
      float dv = val - mu;
      float var = waveSum64(dv * dv) * (1.f / 64.f);
      M.p.x0[r][c] = dv * rsqrtf(var + 1e-5f) * g0[c] + b0[c];
    }
    __syncthreads();
    if (tid < 128) {
      int r = tid >> 6, c = tid & 63;
      int row = u * 2 + r;
      int b = row >> 7, n = row & 127;
      float aq = 0, ak = 0, av = 0;
      for (int cc = 0; cc < 64; cc++) {
        float x = M.p.x0[r][cc];
        aq += x * Wq0[cc * 64 + c];
        ak += x * Wk0[cc * 64 + c];
        av += x * Wv0[cc * 64 + c];
      }
      int h = c >> 4, d = c & 15;
      size_t o0 = ((size_t)((b * 4 + h) * 128 + n)) * 16 + d;
      q0[o0] = aq; k0[o0] = ak; v0[o0] = av;
    }
    __syncthreads();
  }
  grid.sync();

  // ---- P2: attn layer 0 ----
  for (int u = bid; u < 1024; u += G)
    att_body<0>(M, u, coords, tab, q0, k0, v0, q1, k1, v1, out0, out1, tid);
  grid.sync();

  // ---- P3: post0 + ff0 + proj1 ----
  for (int u = bid; u < 1024; u += G) {
    node_body<0>(M, u * 2 + 0, Wo0, bo0, Wo1, gn, bn, g2, b2w, F1, fb1, F2, fb2, Wf1,
                 g0 + 64, b0 + 64, Wq0 + 4096, Wk0 + 4096, Wv0 + 4096, Wq1 + 4096,
                 Wk1 + 4096, Wv1 + 4096, out0, out1, f0, q0, k0, v0, q1, k1, v1, tid);
    node_body<0>(M, u * 2 + 1, Wo0, bo0, Wo1, gn, bn, g2, b2w, F1, fb1, F2, fb2, Wf1,
                 g0 + 64, b0 + 64, Wq0 + 4096, Wk0 + 4096, Wv0 + 4096, Wq1 + 4096,
                 Wk1 + 4096, Wv1 + 4096, out0, out1, f0, q0, k0, v0, q1, k1, v1, tid);
  }
  grid.sync();

  // ---- P4: attn layer 1 ----
  for (int u = bid; u < 1024; u += G)
    att_body<1>(M, u, coords, tab + 16384, q0, k0, v0, q1, k1, v1, out0, out1, tid);
  grid.sync();

  // ---- P5: post1 + ff1 (f0 only) ----
  for (int u = bid; u < 1024; u += G) {
    node_body<1>(M, u * 2 + 0, Wo0 + 4096, bo0 + 64, Wo1 + 4096, gn + 64, bn + 64,
                 g2 + 64, b2w + 64, F1 + 16384, fb1 + 256, F2 + 16384, fb2 + 64,
                 Wf1 + 4096, nullptr, nullptr, nullptr, nullptr, nullptr, nullptr,
                 nullptr, nullptr, out0, out1, f0, q0, k0, v0, q1, k1, v1, tid);
    node_body<1>(M, u * 2 + 1, Wo0 + 4096, bo0 + 64, Wo1 + 4096, gn + 64, bn + 64,
                 g2 + 64, b2w + 64, F1 + 16384, fb1 + 256, F2 + 16384, fb2 + 64,
                 Wf1 + 4096, nullptr, nullptr, nullptr, nullptr, nullptr, nullptr,
                 nullptr, nullptr, out0, out1, f0, q0, k0, v0, q1, k1, v1, tid);
  }
  grid.sync();

  // ---- P6: final pool + Wout ----
  for (int u = bid; u < 16; u += G) {
    if (tid < 64) {
      int c = tid;
      float s = 0;
      for (int n = 0; n < 128; n++) s += f0[((size_t)u * 128 + n) * 64 + c];
      M.f.ps[c] = s * (1.f / 128.f);
    }
    __syncthreads();
    if (tid < 19) {
      float a = bout[tid];
      for (int k = 0; k < 64; k++) a += M.f.ps[k] * Wout[k * 19 + tid];
      if (isbf) ((bf16*)dout)[u * 19 + tid] = __float2bfloat16(a);
      else ((float*)dout)[u * 19 + tid] = a;
    }
    __syncthreads();
  }
}

static const int g_nelem[30] = {
    22528, 6144, 704, 64,
    8192, 8192, 8192, 8192, 8192, 8192,
    1024, 64, 1024, 32,
    8192, 128, 8192,
    128, 128, 128, 128, 128, 128,
    32768, 512, 32768, 128,
    8192, 1216, 19};

extern "C" void kernel_launch(void* const* d_in, const int* in_sizes, int n_in, void* d_out,
                              int out_size, void* d_ws, size_t ws_size, hipStream_t stream) {
  (void)in_sizes; (void)n_in; (void)out_size; (void)ws_size;

  int offs[31];
  offs[0] = 0;
  for (int i = 0; i < 30; i++) offs[i + 1] = offs[i] + g_nelem[i];

  float* conv = (float*)d_ws;
  float* p = conv + 173632;
  float* f0 = p; p += 131072;
  float* q0 = p; p += 131072;
  float* k0 = p; p += 131072;
  float* v0 = p; p += 131072;
  float* q1 = p; p += 393216;
  float* k1 = p; p += 393216;
  float* v1 = p; p += 393216;
  float* out0 = p; p += 131072;
  float* out1 = p; p += 393216;
  float2* tab2 = (float2*)p; p += 65536;

  ConvArgs ca;
  for (int i = 0; i < 30; i++) ca.src[i] = d_in[i];
  for (int i = 0; i < 31; i++) ca.off[i] = offs[i];

  int maxB = 0;
  hipOccupancyMaxActiveBlocksPerMultiprocessor(&maxB, (const void*)k_mega, 256, 0);
  if (maxB < 1) maxB = 1;
  long long grid = (long long)maxB * 256;  // 256 CUs on MI355X
  if (grid > 1024) grid = 1024;

  void* dout = d_out;
  void* kargs[] = {&ca, &conv, &tab2, &f0, &q0, &k0, &v0, &q1, &k1, &v1, &out0, &out1, &dout};
  hipLaunchCooperativeKernel((const void*)k_mega, dim3((unsigned)grid), dim3(256), kargs, 0,
                             stream);
}

// Round 13
// 111.776 us; speedup vs baseline: 6.8811x; 6.8811x over previous
//
#include <hip/hip_runtime.h>
#include <hip/hip_bf16.h>

// SE3EncoderDecoderQM9: B=16,N=128,H=4,DH=16,C=64,NRBF=16,L=2, R=10
// 6-launch pipeline: tab+proj0, attn0, node0(post+ff+proj1), attn1,
// node1(f0 only), final. NO conversion buffer: all kernels read raw
// bf16/f32 inputs via per-block dtype vote (templated bodies). q/k/v
// stored bf16 (bit-identical to prior in-attn RNE conversion).

typedef __hip_bfloat16 bf16;
typedef unsigned short u16;
typedef __attribute__((ext_vector_type(8))) short short8;
typedef __attribute__((ext_vector_type(4))) float float4v;

__device__ __forceinline__ float waveSum64(float v) {
#pragma unroll
  for (int m = 1; m < 64; m <<= 1) v += __shfl_xor(v, m, 64);
  return v;
}
__device__ __forceinline__ float bits2f(u16 b) {
  return __uint_as_float(((unsigned int)b) << 16);
}
__device__ __forceinline__ u16 f2bu(float f) {
  unsigned int u = __float_as_uint(f);
  u = (u + 0x7fffu + ((u >> 16) & 1u)) >> 16;  // RNE
  return (u16)u;
}
__device__ __forceinline__ float ldw(const u16* p, int i) { return bits2f(p[i]); }
__device__ __forceinline__ float ldw(const float* p, int i) { return p[i]; }
__device__ __forceinline__ float ldraw(const void* p, int i, bool isbf) {
  return isbf ? bits2f(((const u16*)p)[i]) : ((const float*)p)[i];
}
__device__ __forceinline__ int voteSlice(const u16* u, int start, int stride) {
  int insane = 0;
  for (int e = start; e < 1024; e += stride) {
    float f = bits2f(u[2 * e]);
    float af = fabsf(f);
    insane += (!(af < 1e4f) || (f != 0.f && af < 1e-20f)) ? 1 : 0;
  }
  return insane;
}

// ================= tab + proj0 (fused launch) =================
template <typename WT>
__device__ void proj0_body(float (*fs)[12], float (*x0s)[64], const WT* feats,
                           const WT* W_emb, const WT* b_emb, const WT* g0,
                           const WT* b0, const WT* Wq0, const WT* Wk0,
                           const WT* Wv0, float* __restrict__ f0, u16* __restrict__ q0,
                           u16* __restrict__ k0, u16* __restrict__ v0, int u, int tid) {
  int wv = tid >> 6, c = tid & 63;
  int row = u * 4 + wv;
  int b = row >> 7, n = row & 127;
  if (c < 11) fs[wv][c] = ldw(feats, row * 11 + c);
  __syncthreads();
  float val = ldw(b_emb, c);
#pragma unroll
  for (int k = 0; k < 11; k++) val += fs[wv][k] * ldw(W_emb, k * 64 + c);
  f0[(size_t)row * 64 + c] = val;
  float mu = waveSum64(val) * (1.f / 64.f);
  float dv = val - mu;
  float var = waveSum64(dv * dv) * (1.f / 64.f);
  x0s[wv][c] = dv * rsqrtf(var + 1e-5f) * ldw(g0, c) + ldw(b0, c);
  __syncthreads();
  float aq = 0, ak = 0, av = 0;
  for (int cc = 0; cc < 64; cc++) {
    float x = x0s[wv][cc];
    aq += x * ldw(Wq0, cc * 64 + c);
    ak += x * ldw(Wk0, cc * 64 + c);
    av += x * ldw(Wv0, cc * 64 + c);
  }
  int h = c >> 4, d = c & 15;
  size_t o0 = ((size_t)((b * 4 + h) * 128 + n)) * 16 + d;
  q0[o0] = f2bu(aq);
  k0[o0] = f2bu(ak);
  v0[o0] = f2bu(av);
}

__global__ void __launch_bounds__(256) k_tabproj0(
    const void* feats, const void* rW1, const void* rb1, const void* rW2,
    const void* rb2, const void* W_emb, const void* b_emb, const void* g0,
    const void* b0, const void* Wq0, const void* Wk0, const void* Wv0,
    float2* __restrict__ tab, float* __restrict__ f0, u16* __restrict__ q0,
    u16* __restrict__ k0, u16* __restrict__ v0) {
  __shared__ int cnt;
  __shared__ float sW1[512], sb1[32], sW2[512], sb2[16];
  __shared__ float fs[4][12], x0s[4][64];
  int tid = threadIdx.x;
  if (tid == 0) cnt = 0;
  __syncthreads();
  atomicAdd(&cnt, voteSlice((const u16*)feats, tid, 256));
  __syncthreads();
  bool isbf = (cnt <= 100);
  int bid = blockIdx.x;

  if (bid < 8) {
    int g = bid * 256 + tid;
    int l = g >> 10, bin = g & 1023;
    for (int k = tid; k < 512; k += 256) {
      sW1[k] = ldraw(rW1, l * 512 + k, isbf);
      sW2[k] = ldraw(rW2, l * 512 + k, isbf);
    }
    if (tid < 32) sb1[tid] = ldraw(rb1, l * 32 + tid, isbf);
    if (tid < 16) sb2[tid] = ldraw(rb2, l * 16 + tid, isbf);
    __syncthreads();
    float w[2][16];
#pragma unroll
    for (int t = 0; t < 2; ++t) {
      float d = (float)(bin + t) * 0.01f;
      float rbf[16];
#pragma unroll
      for (int r = 0; r < 16; ++r) {
        float x = d - (10.0f / 15.0f) * (float)r;
        rbf[r] = __expf(-x * x * 1.28f);
      }
#pragma unroll
      for (int o = 0; o < 16; ++o) w[t][o] = sb2[o];
      for (int k = 0; k < 32; ++k) {
        float acc = sb1[k];
#pragma unroll
        for (int r = 0; r < 16; ++r) acc += rbf[r] * sW1[r * 32 + k];
        acc = fmaxf(acc, 0.f);
#pragma unroll
        for (int o = 0; o < 16; ++o) w[t][o] += acc * sW2[k * 16 + o];
      }
    }
#pragma unroll
    for (int o = 0; o < 16; ++o)
      tab[l * 16384 + bin * 16 + o] = make_float2(w[0][o], w[1][o]);
  } else {
    int u = bid - 8;
    if (isbf)
      proj0_body<u16>(fs, x0s, (const u16*)feats, (const u16*)W_emb, (const u16*)b_emb,
                      (const u16*)g0, (const u16*)b0, (const u16*)Wq0, (const u16*)Wk0,
                      (const u16*)Wv0, f0, q0, k0, v0, u, tid);
    else
      proj0_body<float>(fs, x0s, (const float*)feats, (const float*)W_emb,
                        (const float*)b_emb, (const float*)g0, (const float*)b0,
                        (const float*)Wq0, (const float*)Wk0, (const float*)Wv0, f0, q0,
                        k0, v0, u, tid);
  }
}

// ================= attention (r7-r11 validated core, bf16 q/k/v) =================
template <int HASF1>
__global__ void __launch_bounds__(256, 4) k_attn(
    const void* featsraw, const void* coords, const float2* __restrict__ tab,
    const u16* __restrict__ q0, const u16* __restrict__ k0, const u16* __restrict__ v0,
    const u16* __restrict__ q1, const u16* __restrict__ k1, const u16* __restrict__ v1,
    float* __restrict__ out0, float* __restrict__ out1) {
  __shared__ union {
    u16 ks[128][64];
    u16 A16[64][128];
  } U;
  __shared__ unsigned int S01[8][128];
  __shared__ u16 Bt[64][128];
  __shared__ float cs[3][128];
  __shared__ int cnt;

  int tid = threadIdx.x;
  if (tid == 0) cnt = 0;
  __syncthreads();
  atomicAdd(&cnt, voteSlice((const u16*)featsraw, tid, 256));
  __syncthreads();
  bool isbf = (cnt <= 100);

  int bid = blockIdx.x;
  int bh = bid & 63, it = bid >> 6;
  int h = bh & 3, b = bh >> 2;
  int ibase = it * 8;
  size_t rowbase = (size_t)bh * 128;
  int lane = tid & 63, waveid = tid >> 6;
  int ln = lane & 15, lg = lane >> 4;

  short8 P0f = {0, 0, 0, 0, 0, 0, 0, 0};
  short8 P1f = {0, 0, 0, 0, 0, 0, 0, 0};
  short8 P2f = {0, 0, 0, 0, 0, 0, 0, 0};
  if (ln < 8) {
    int i = ibase + ln;
    if (HASF1) {
      const u16* q1p = q1 + (rowbase + i) * 48;
      P0f = *(const short8*)&q1p[lg * 8];
      if (lg < 2) P1f = *(const short8*)&q1p[32 + lg * 8];
    }
    if (lg >= 2) {
      const u16* q0p = q0 + (rowbase + i) * 16;
      P2f = *(const short8*)&q0p[(lg - 2) * 8];
    }
  }

  if (HASF1) {
    for (int e = tid; e < 2048; e += 256) {
      int j = e >> 4, t0 = (e & 15) * 4;
      ushort4 pk;
      if (t0 < 48) pk = *(const ushort4*)&k1[(rowbase + j) * 48 + t0];
      else pk = *(const ushort4*)&k0[(rowbase + j) * 16 + (t0 - 48)];
      int g = t0 >> 3;
      *(ushort4*)&U.ks[j][((g ^ (j & 7)) << 3) | (t0 & 7)] = pk;
    }
  } else {
    for (int e = tid; e < 1024; e += 256) {
      int j = e >> 3, t0 = 32 + (e & 7) * 4;
      ushort4 pk = {0, 0, 0, 0};
      if (t0 >= 48) pk = *(const ushort4*)&k0[(rowbase + j) * 16 + (t0 - 48)];
      int g = t0 >> 3;
      *(ushort4*)&U.ks[j][((g ^ (j & 7)) << 3) | (t0 & 7)] = pk;
    }
  }
  for (int e = tid; e < 512; e += 256) {
    int j = e >> 2, q = e & 3;
    ushort4 f = *(const ushort4*)&v0[(rowbase + j) * 16 + q * 4];
    int jhi = j >> 3, jl = j & 7;
#pragma unroll
    for (int i2 = 0; i2 < 4; ++i2) {
      int d = q * 4 + i2;
      int sl = (jhi ^ d) << 3;
      u16 fv = (i2 == 0) ? f.x : (i2 == 1) ? f.y : (i2 == 2) ? f.z : f.w;
      Bt[d][sl | jl] = fv;
      if (!HASF1) {
        Bt[16 + d][sl | jl] = 0;
        Bt[32 + d][sl | jl] = 0;
        Bt[48 + d][sl | jl] = 0;
      }
    }
  }
  if (HASF1) {
    for (int e = tid; e < 1536; e += 256) {
      int j = e / 12, q = e - j * 12;
      ushort4 f = *(const ushort4*)&v1[(rowbase + j) * 48 + q * 4];
      int jhi = j >> 3, jl = j & 7;
#pragma unroll
      for (int i2 = 0; i2 < 4; ++i2) {
        int flat = q * 4 + i2;
        int d = flat / 3, vv = flat - d * 3;
        int sl = (jhi ^ d) << 3;
        u16 fv = (i2 == 0) ? f.x : (i2 == 1) ? f.y : (i2 == 2) ? f.z : f.w;
        Bt[(vv + 1) * 16 + d][sl | jl] = fv;
      }
    }
  }
  if (tid < 128) {
    cs[0][tid] = ldraw(coords, ((int)b * 128 + tid) * 3 + 0, isbf);
    cs[1][tid] = ldraw(coords, ((int)b * 128 + tid) * 3 + 1, isbf);
    cs[2][tid] = ldraw(coords, ((int)b * 128 + tid) * 3 + 2, isbf);
  }
  __syncthreads();  // bar1

#pragma unroll
  for (int q = 0; q < 2; ++q) {
    int j = (waveid * 2 + q) * 16 + ln;
    int swz = j & 7;
    short8 bk1 = *(const short8*)&U.ks[j][(((4 + lg) ^ swz) << 3)];
    float4v a0 = {0.f, 0.f, 0.f, 0.f};
    a0 = __builtin_amdgcn_mfma_f32_16x16x32_bf16(P2f, bk1, a0, 0, 0, 0);
    float4v a1 = {0.f, 0.f, 0.f, 0.f};
    if (HASF1) {
      short8 bk0 = *(const short8*)&U.ks[j][((lg ^ swz) << 3)];
      a1 = __builtin_amdgcn_mfma_f32_16x16x32_bf16(P0f, bk0, a1, 0, 0, 0);
      a1 = __builtin_amdgcn_mfma_f32_16x16x32_bf16(P1f, bk1, a1, 0, 0, 0);
    }
    if (lg < 2) {
#pragma unroll
      for (int r = 0; r < 4; ++r) {
        unsigned int pk =
            (unsigned int)f2bu(a0[r]) | ((unsigned int)f2bu(a1[r]) << 16);
        S01[lg * 4 + r][j] = pk;
      }
    }
  }
  __syncthreads();  // bar2

  {
    int row = tid >> 5, jg = tid & 31;
    int i = ibase + row;
    float cix = cs[0][i], ciy = cs[1][i], ciz = cs[2][i];
    uint4 sv = *(const uint4*)&S01[row][jg * 4];
    float e4[4], w4[4][4], yv[4][3];
    int nmmask = 0;
    float mx = -3e38f;
#pragma unroll
    for (int jj = 0; jj < 4; ++jj) {
      int j = jg * 4 + jj;
      float rx = cs[0][j] - cix;
      float ry = cs[1][j] - ciy;
      float rz = cs[2][j] - ciz;
      float dd = sqrtf(rx * rx + ry * ry + rz * rz + 1e-8f);
      float inv = 1.f / dd;
      yv[jj][0] = rx * inv; yv[jj][1] = ry * inv; yv[jj][2] = rz * inv;
      float tt = fminf(dd, 10.229f) * 100.f;
      int i0 = (int)tt;
      float fr = tt - (float)i0;
      const float2* Tp = tab + (i0 << 4) + h;
      float2 t0 = Tp[0], t1 = Tp[4], t2 = Tp[8], t3 = Tp[12];
      w4[jj][0] = t0.x + fr * (t0.y - t0.x);
      w4[jj][1] = t1.x + fr * (t1.y - t1.x);
      w4[jj][2] = t2.x + fr * (t2.y - t2.x);
      w4[jj][3] = t3.x + fr * (t3.y - t3.x);
      unsigned int sw = (jj == 0) ? sv.x : (jj == 1) ? sv.y : (jj == 2) ? sv.z : sv.w;
      float s0j = bits2f((u16)(sw & 0xffffu));
      float s1j = bits2f((u16)(sw >> 16));
      float sim = (s0j * w4[jj][0] + (HASF1 ? s1j * w4[jj][3] : 0.f)) * 0.25f;
      bool nm = (dd <= 10.0f) && (j != i);
      if (nm) nmmask |= (1 << jj);
      sim = nm ? sim : -1e9f;
      e4[jj] = sim;
      mx = fmaxf(mx, sim);
    }
#pragma unroll
    for (int m = 1; m < 32; m <<= 1) mx = fmaxf(mx, __shfl_xor(mx, m, 64));
    float ssum = 0.f;
#pragma unroll
    for (int jj = 0; jj < 4; ++jj) {
      e4[jj] = __expf(e4[jj] - mx);
      ssum += e4[jj];
    }
#pragma unroll
    for (int m = 1; m < 32; m <<= 1) ssum += __shfl_xor(ssum, m, 64);
    float rinv = 1.f / ssum;
    float aj[4];
#pragma unroll
    for (int jj = 0; jj < 4; ++jj)
      aj[jj] = ((nmmask >> jj) & 1) ? e4[jj] * rinv : 0.f;
#pragma unroll
    for (int s = 0; s < 8; ++s) {
      u16 t4[4];
#pragma unroll
      for (int jj = 0; jj < 4; ++jj) {
        float v;
        if (s == 0) v = aj[jj] * w4[jj][0];
        else if (s < 4) v = aj[jj] * w4[jj][2] * yv[jj][s - 1];
        else if (s < 7) v = aj[jj] * w4[jj][1] * yv[jj][s - 4];
        else v = aj[jj] * w4[jj][3];
        t4[jj] = f2bu(v);
      }
      ushort4 pk = {t4[0], t4[1], t4[2], t4[3]};
      int arow = row * 8 + s;
      int g = jg >> 1;
      *(ushort4*)&U.A16[arow][(((g ^ (arow & 15)) << 3) | ((jg & 1) * 4))] = pk;
    }
  }
  __syncthreads();  // bar3

  float4v acc[4];
#pragma unroll
  for (int nt = 0; nt < 4; ++nt) acc[nt] = (float4v){0.f, 0.f, 0.f, 0.f};
  int m = waveid * 16 + ln;
#pragma unroll
  for (int kst = 0; kst < 4; ++kst) {
    int gk = kst * 4 + lg;
    short8 af = *(const short8*)&U.A16[m][((gk ^ ln) << 3)];
#pragma unroll
    for (int nt = 0; nt < 4; ++nt) {
      short8 bf = *(const short8*)&Bt[nt * 16 + ln][((gk ^ ln) << 3)];
      acc[nt] = __builtin_amdgcn_mfma_f32_16x16x32_bf16(af, bf, acc[nt], 0, 0, 0);
    }
  }
  {
    int qr = waveid * 2 + (lg >> 1);
    size_t orow = rowbase + ibase + qr;
    if ((lg & 1) == 0) {
      out0[orow * 16 + ln] = acc[0][0] + acc[1][1] + acc[2][2] + acc[3][3];
    } else {
#pragma unroll
      for (int vv = 0; vv < 3; ++vv)
        out1[orow * 48 + ln * 3 + vv] = acc[0][vv] + acc[1 + vv][3];
    }
  }
}

// ================= node: post + FF (+ next proj), r9 structure =================
struct NodeS {
  float pp[4][12][64];
  float o0s[64], rs[64], xnl[64], hb[256];
  float o1s[192], f1g[192], f1n[192], x0s[64];
};

template <int LAST, typename WT>
__device__ void node_body(NodeS& S, int row, const WT* Wo0, const WT* bo0,
                          const WT* Wo1, const WT* gn, const WT* bn, const WT* g2,
                          const WT* b2w, const WT* F1, const WT* fb1, const WT* F2,
                          const WT* fb2, const WT* Wf1, const WT* g0n, const WT* b0n,
                          const WT* Wq0n, const WT* Wk0n, const WT* Wv0n,
                          const WT* Wq1n, const WT* Wk1n, const WT* Wv1n,
                          const float* __restrict__ out0, const float* __restrict__ out1,
                          float* __restrict__ f0, u16* __restrict__ q0,
                          u16* __restrict__ k0, u16* __restrict__ v0,
                          u16* __restrict__ q1, u16* __restrict__ k1,
                          u16* __restrict__ v1, int tid) {
  int g = tid >> 6, c = tid & 63;
  int b = row >> 7, n = row & 127;

  if (tid < 64) {
    int h = tid >> 4, d = tid & 15;
    S.o0s[tid] = out0[((size_t)((b * 4 + h) * 128 + n)) * 16 + d];
  } else if (!LAST) {
    int t = tid - 64;
    int cc = t / 3, v = t - cc * 3;
    int h = cc >> 4, d = cc & 15;
    S.o1s[t] = out1[((size_t)((b * 4 + h) * 128 + n)) * 48 + d * 3 + v];
  }
  __syncthreads();
  {
    float a0 = 0, ax = 0, ay = 0, az = 0;
#pragma unroll
    for (int mi = 0; mi < 16; ++mi) {
      int m = g * 16 + mi;
      a0 += S.o0s[m] * ldw(Wo0, m * 64 + c);
      if (!LAST) {
        float w = ldw(Wo1, m * 64 + c);
        ax += S.o1s[m * 3 + 0] * w;
        ay += S.o1s[m * 3 + 1] * w;
        az += S.o1s[m * 3 + 2] * w;
      }
    }
    S.pp[g][0][c] = a0;
    if (!LAST) { S.pp[g][1][c] = ax; S.pp[g][2][c] = ay; S.pp[g][3][c] = az; }
  }
  __syncthreads();
  if (tid < 64) {
    float a0 = ldw(bo0, c) + S.pp[0][0][c] + S.pp[1][0][c] + S.pp[2][0][c] + S.pp[3][0][c];
    float f0p = f0[(size_t)row * 64 + c] + a0;
    S.rs[c] = f0p;
    if (!LAST) {
      float fx = S.pp[0][1][c] + S.pp[1][1][c] + S.pp[2][1][c] + S.pp[3][1][c];
      float fy = S.pp[0][2][c] + S.pp[1][2][c] + S.pp[2][2][c] + S.pp[3][2][c];
      float fz = S.pp[0][3][c] + S.pp[1][3][c] + S.pp[2][3][c] + S.pp[3][3][c];
      float n1 = sqrtf(fx * fx + fy * fy + fz * fz + 1e-8f);
      float gate = fmaxf(n1 * ldw(gn, c) + ldw(bn, c), 0.f);
      float sc = gate / n1;
      S.f1g[c * 3 + 0] = fx * sc;
      S.f1g[c * 3 + 1] = fy * sc;
      S.f1g[c * 3 + 2] = fz * sc;
    }
    float mu = waveSum64(f0p) * (1.f / 64.f);
    float dv = f0p - mu;
    float var = waveSum64(dv * dv) * (1.f / 64.f);
    S.xnl[c] = dv * rsqrtf(var + 1e-5f) * ldw(g2, c) + ldw(b2w, c);
  }
  __syncthreads();
  {
    float a = ldw(fb1, tid);
    for (int cc = 0; cc < 64; ++cc) a += S.xnl[cc] * ldw(F1, cc * 256 + tid);
    S.hb[tid] = fmaxf(a, 0.f);
  }
  __syncthreads();
  {
    float s = 0;
#pragma unroll 8
    for (int kk = 0; kk < 64; ++kk) {
      int k = g * 64 + kk;
      s += S.hb[k] * ldw(F2, k * 64 + c);
    }
    S.pp[g][4][c] = s;
    if (!LAST) {
      float sx = 0, sy = 0, sz = 0;
#pragma unroll
      for (int mi = 0; mi < 16; ++mi) {
        int m = g * 16 + mi;
        float w = ldw(Wf1, m * 64 + c);
        sx += S.f1g[m * 3 + 0] * w;
        sy += S.f1g[m * 3 + 1] * w;
        sz += S.f1g[m * 3 + 2] * w;
      }
      S.pp[g][5][c] = sx; S.pp[g][6][c] = sy; S.pp[g][7][c] = sz;
    }
  }
  __syncthreads();
  if (tid < 64) {
    float f0n = S.rs[c] + ldw(fb2, c) + S.pp[0][4][c] + S.pp[1][4][c] + S.pp[2][4][c] +
                S.pp[3][4][c];
    f0[(size_t)row * 64 + c] = f0n;
    if (!LAST) {
      S.f1n[c * 3 + 0] =
          S.f1g[c * 3 + 0] + S.pp[0][5][c] + S.pp[1][5][c] + S.pp[2][5][c] + S.pp[3][5][c];
      S.f1n[c * 3 + 1] =
          S.f1g[c * 3 + 1] + S.pp[0][6][c] + S.pp[1][6][c] + S.pp[2][6][c] + S.pp[3][6][c];
      S.f1n[c * 3 + 2] =
          S.f1g[c * 3 + 2] + S.pp[0][7][c] + S.pp[1][7][c] + S.pp[2][7][c] + S.pp[3][7][c];
      float mu2 = waveSum64(f0n) * (1.f / 64.f);
      float dv2 = f0n - mu2;
      float var2 = waveSum64(dv2 * dv2) * (1.f / 64.f);
      S.x0s[c] = dv2 * rsqrtf(var2 + 1e-5f) * ldw(g0n, c) + ldw(b0n, c);
    }
  }
  if (LAST) return;
  __syncthreads();
  {
    float q[12];
#pragma unroll
    for (int j = 0; j < 12; ++j) q[j] = 0.f;
#pragma unroll
    for (int t = 0; t < 16; ++t) {
      int cc = g * 16 + t;
      float x = S.x0s[cc];
      float fx = S.f1n[cc * 3 + 0], fy = S.f1n[cc * 3 + 1], fz = S.f1n[cc * 3 + 2];
      q[0] += x * ldw(Wq0n, cc * 64 + c);
      q[1] += x * ldw(Wk0n, cc * 64 + c);
      q[2] += x * ldw(Wv0n, cc * 64 + c);
      float w = ldw(Wq1n, cc * 64 + c);
      q[3] += fx * w; q[4] += fy * w; q[5] += fz * w;
      w = ldw(Wk1n, cc * 64 + c);
      q[6] += fx * w; q[7] += fy * w; q[8] += fz * w;
      w = ldw(Wv1n, cc * 64 + c);
      q[9] += fx * w; q[10] += fy * w; q[11] += fz * w;
    }
#pragma unroll
    for (int j = 0; j < 12; ++j) S.pp[g][j][c] = q[j];
  }
  __syncthreads();
  if (tid < 64) {
    int h = c >> 4, d = c & 15;
    size_t rb = (size_t)((b * 4 + h) * 128 + n);
    float rr[12];
#pragma unroll
    for (int j = 0; j < 12; ++j)
      rr[j] = S.pp[0][j][c] + S.pp[1][j][c] + S.pp[2][j][c] + S.pp[3][j][c];
    size_t o0 = rb * 16 + d;
    size_t o1 = rb * 48 + d * 3;
    q0[o0] = f2bu(rr[0]); k0[o0] = f2bu(rr[1]); v0[o0] = f2bu(rr[2]);
    q1[o1 + 0] = f2bu(rr[3]); q1[o1 + 1] = f2bu(rr[4]); q1[o1 + 2] = f2bu(rr[5]);
    k1[o1 + 0] = f2bu(rr[6]); k1[o1 + 1] = f2bu(rr[7]); k1[o1 + 2] = f2bu(rr[8]);
    v1[o1 + 0] = f2bu(rr[9]); v1[o1 + 1] = f2bu(rr[10]); v1[o1 + 2] = f2bu(rr[11]);
  }
}

template <int LAST>
__global__ void __launch_bounds__(256) k_node(
    const void* featsraw, const void* Wq0, const void* Wk0, const void* Wv0,
    const void* Wq1, const void* Wk1, const void* Wv1, const void* Wo0,
    const void* bo0, const void* Wo1, const void* g0, const void* b0, const void* gn,
    const void* bn, const void* g2, const void* b2w, const void* F1, const void* fb1,
    const void* F2, const void* fb2, const void* Wf1, const float* __restrict__ out0,
    const float* __restrict__ out1, float* __restrict__ f0, u16* __restrict__ q0,
    u16* __restrict__ k0, u16* __restrict__ v0, u16* __restrict__ q1,
    u16* __restrict__ k1, u16* __restrict__ v1, int l) {
  __shared__ NodeS S;
  __shared__ int cnt;
  int tid = threadIdx.x;
  if (tid == 0) cnt = 0;
  __syncthreads();
  atomicAdd(&cnt, voteSlice((const u16*)featsraw, tid, 256));
  __syncthreads();
  bool isbf = (cnt <= 100);
  int row = blockIdx.x;
  int l2 = l + 1;
  if (isbf) {
    node_body<LAST, u16>(
        S, row, (const u16*)Wo0 + l * 4096, (const u16*)bo0 + l * 64,
        (const u16*)Wo1 + l * 4096, (const u16*)gn + l * 64, (const u16*)bn + l * 64,
        (const u16*)g2 + l * 64, (const u16*)b2w + l * 64, (const u16*)F1 + l * 16384,
        (const u16*)fb1 + l * 256, (const u16*)F2 + l * 16384, (const u16*)fb2 + l * 64,
        (const u16*)Wf1 + l * 4096, (const u16*)g0 + l2 * 64, (const u16*)b0 + l2 * 64,
        (const u16*)Wq0 + l2 * 4096, (const u16*)Wk0 + l2 * 4096,
        (const u16*)Wv0 + l2 * 4096, (const u16*)Wq1 + l2 * 4096,
        (const u16*)Wk1 + l2 * 4096, (const u16*)Wv1 + l2 * 4096, out0, out1, f0, q0,
        k0, v0, q1, k1, v1, tid);
  } else {
    node_body<LAST, float>(
        S, row, (const float*)Wo0 + l * 4096, (const float*)bo0 + l * 64,
        (const float*)Wo1 + l * 4096, (const float*)gn + l * 64,
        (const float*)bn + l * 64, (const float*)g2 + l * 64,
        (const float*)b2w + l * 64, (const float*)F1 + l * 16384,
        (const float*)fb1 + l * 256, (const float*)F2 + l * 16384,
        (const float*)fb2 + l * 64, (const float*)Wf1 + l * 4096,
        (const float*)g0 + l2 * 64, (const float*)b0 + l2 * 64,
        (const float*)Wq0 + l2 * 4096, (const float*)Wk0 + l2 * 4096,
        (const float*)Wv0 + l2 * 4096, (const float*)Wq1 + l2 * 4096,
        (const float*)Wk1 + l2 * 4096, (const float*)Wv1 + l2 * 4096, out0, out1, f0,
        q0, k0, v0, q1, k1, v1, tid);
  }
}

// ================= final =================
__global__ void k_final(const void* featsraw, const float* __restrict__ f0,
                        const void* Wout, const void* bout, void* __restrict__ out) {
  int b = blockIdx.x;
  int c = threadIdx.x;  // 0..63
  __shared__ float ps[64];
  int insane = voteSlice((const u16*)featsraw, c, 64);
  float cntf = waveSum64((float)insane);
  bool isbf = (cntf <= 100.f);
  float s = 0;
  for (int n = 0; n < 128; n++) s += f0[((size_t)b * 128 + n) * 64 + c];
  ps[c] = s * (1.f / 128.f);
  __syncthreads();
  if (c < 19) {
    float a = ldraw(bout, c, isbf);
    for (int k = 0; k < 64; k++) a += ps[k] * ldraw(Wout, k * 19 + c, isbf);
    if (isbf) ((bf16*)out)[b * 19 + c] = __float2bfloat16(a);
    else ((float*)out)[b * 19 + c] = a;
  }
}

extern "C" void kernel_launch(void* const* d_in, const int* in_sizes, int n_in, void* d_out,
                              int out_size, void* d_ws, size_t ws_size, hipStream_t stream) {
  (void)in_sizes; (void)n_in; (void)out_size; (void)ws_size;

  const void* feats = d_in[0];
  const void* coords = d_in[1];
  const void* W_emb = d_in[2];
  const void* b_emb = d_in[3];
  const void* Wq0 = d_in[4];
  const void* Wk0 = d_in[5];
  const void* Wv0 = d_in[6];
  const void* Wq1 = d_in[7];
  const void* Wk1 = d_in[8];
  const void* Wv1 = d_in[9];
  const void* rW1 = d_in[10];
  const void* rb1 = d_in[11];
  const void* rW2 = d_in[12];
  const void* rb2 = d_in[13];
  const void* Wo0 = d_in[14];
  const void* bo0 = d_in[15];
  const void* Wo1 = d_in[16];
  const void* g0 = d_in[17];
  const void* b0 = d_in[18];
  const void* gn = d_in[19];
  const void* bn = d_in[20];
  const void* g2 = d_in[21];
  const void* b2w = d_in[22];
  const void* F1 = d_in[23];
  const void* fb1 = d_in[24];
  const void* F2 = d_in[25];
  const void* fb2 = d_in[26];
  const void* Wf1 = d_in[27];
  const void* Wout = d_in[28];
  const void* bout = d_in[29];

  float* fp = (float*)d_ws;
  float* f0 = fp; fp += 131072;
  float* out0 = fp; fp += 131072;
  float* out1 = fp; fp += 393216;
  float2* tab2 = (float2*)fp; fp += 65536;  // 32768 float2
  u16* up = (u16*)fp;
  u16* q0u = up; up += 131072;
  u16* k0u = up; up += 131072;
  u16* v0u = up; up += 131072;
  u16* q1u = up; up += 393216;
  u16* k1u = up; up += 393216;
  u16* v1u = up; up += 393216;

  // launch 1: radial table (blocks 0-7) + proj0 (blocks 8-519)
  k_tabproj0<<<520, 256, 0, stream>>>(feats, rW1, rb1, rW2, rb2, W_emb, b_emb, g0, b0,
                                      Wq0, Wk0, Wv0, tab2, f0, q0u, k0u, v0u);
  // layer 0
  k_attn<0><<<1024, 256, 0, stream>>>(feats, coords, tab2, q0u, k0u, v0u, q1u, k1u, v1u,
                                      out0, out1);
  k_node<0><<<2048, 256, 0, stream>>>(feats, Wq0, Wk0, Wv0, Wq1, Wk1, Wv1, Wo0, bo0, Wo1,
                                      g0, b0, gn, bn, g2, b2w, F1, fb1, F2, fb2, Wf1,
                                      out0, out1, f0, q0u, k0u, v0u, q1u, k1u, v1u, 0);
  // layer 1
  k_attn<1><<<1024, 256, 0, stream>>>(feats, coords, tab2 + 16384, q0u, k0u, v0u, q1u,
                                      k1u, v1u, out0, out1);
  k_node<1><<<2048, 256, 0, stream>>>(feats, Wq0, Wk0, Wv0, Wq1, Wk1, Wv1, Wo0, bo0, Wo1,
                                      g0, b0, gn, bn, g2, b2w, F1, fb1, F2, fb2, Wf1,
                                      out0, out1, f0, q0u, k0u, v0u, q1u, k1u, v1u, 1);
  // final
  k_final<<<16, 64, 0, stream>>>(feats, f0, Wout, bout, d_out);
}

// Round 14
// 110.694 us; speedup vs baseline: 6.9485x; 1.0098x over previous
//
#include <hip/hip_runtime.h>
#include <hip/hip_bf16.h>

// SE3EncoderDecoderQM9: B=16,N=128,H=4,DH=16,C=64,NRBF=16,L=2, R=10
// 6-launch: tabproj0, attn0, nodeM0(MFMA post+ff+proj1), attn1, nodeM1, final.
// nodeM: 16 rows/block, grid 128; weights staged transposed+swizzled to LDS,
// all GEMMs via mfma_16x16x32_bf16 (per-thread weight loads ~280 -> ~35).

typedef __hip_bfloat16 bf16;
typedef unsigned short u16;
typedef __attribute__((ext_vector_type(8))) short short8;
typedef __attribute__((ext_vector_type(4))) float float4v;

__device__ __forceinline__ float waveSum64(float v) {
#pragma unroll
  for (int m = 1; m < 64; m <<= 1) v += __shfl_xor(v, m, 64);
  return v;
}
__device__ __forceinline__ float bits2f(u16 b) {
  return __uint_as_float(((unsigned int)b) << 16);
}
__device__ __forceinline__ u16 f2bu(float f) {
  unsigned int u = __float_as_uint(f);
  u = (u + 0x7fffu + ((u >> 16) & 1u)) >> 16;  // RNE
  return (u16)u;
}
__device__ __forceinline__ float ldw(const u16* p, int i) { return bits2f(p[i]); }
__device__ __forceinline__ float ldw(const float* p, int i) { return p[i]; }
__device__ __forceinline__ float ldraw(const void* p, int i, bool isbf) {
  return isbf ? bits2f(((const u16*)p)[i]) : ((const float*)p)[i];
}
__device__ __forceinline__ int voteSlice(const u16* u, int start, int stride) {
  int insane = 0;
  for (int e = start; e < 1024; e += stride) {
    float f = bits2f(u[2 * e]);
    float af = fabsf(f);
    insane += (!(af < 1e4f) || (f != 0.f && af < 1e-20f)) ? 1 : 0;
  }
  return insane;
}
// swizzled element offsets (attn-validated pattern)
__device__ __forceinline__ int off64(int row, int t) {
  int g = t >> 3;
  return row * 64 + (((g ^ (row & 7)) << 3) | (t & 7));
}
__device__ __forceinline__ int off256(int row, int t) {
  int g = t >> 3;
  return row * 256 + ((((g & 24) | ((g & 7) ^ (row & 7))) << 3) | (t & 7));
}

// ================= tab + proj0 (fused launch, r13 validated) =================
template <typename WT>
__device__ void proj0_body(float (*fs)[12], float (*x0s)[64], const WT* feats,
                           const WT* W_emb, const WT* b_emb, const WT* g0,
                           const WT* b0, const WT* Wq0, const WT* Wk0,
                           const WT* Wv0, float* __restrict__ f0, u16* __restrict__ q0,
                           u16* __restrict__ k0, u16* __restrict__ v0, int u, int tid) {
  int wv = tid >> 6, c = tid & 63;
  int row = u * 4 + wv;
  int b = row >> 7, n = row & 127;
  if (c < 11) fs[wv][c] = ldw(feats, row * 11 + c);
  __syncthreads();
  float val = ldw(b_emb, c);
#pragma unroll
  for (int k = 0; k < 11; k++) val += fs[wv][k] * ldw(W_emb, k * 64 + c);
  f0[(size_t)row * 64 + c] = val;
  float mu = waveSum64(val) * (1.f / 64.f);
  float dv = val - mu;
  float var = waveSum64(dv * dv) * (1.f / 64.f);
  x0s[wv][c] = dv * rsqrtf(var + 1e-5f) * ldw(g0, c) + ldw(b0, c);
  __syncthreads();
  float aq = 0, ak = 0, av = 0;
  for (int cc = 0; cc < 64; cc++) {
    float x = x0s[wv][cc];
    aq += x * ldw(Wq0, cc * 64 + c);
    ak += x * ldw(Wk0, cc * 64 + c);
    av += x * ldw(Wv0, cc * 64 + c);
  }
  int h = c >> 4, d = c & 15;
  size_t o0 = ((size_t)((b * 4 + h) * 128 + n)) * 16 + d;
  q0[o0] = f2bu(aq);
  k0[o0] = f2bu(ak);
  v0[o0] = f2bu(av);
}

__global__ void __launch_bounds__(256) k_tabproj0(
    const void* feats, const void* rW1, const void* rb1, const void* rW2,
    const void* rb2, const void* W_emb, const void* b_emb, const void* g0,
    const void* b0, const void* Wq0, const void* Wk0, const void* Wv0,
    float2* __restrict__ tab, float* __restrict__ f0, u16* __restrict__ q0,
    u16* __restrict__ k0, u16* __restrict__ v0) {
  __shared__ int cnt;
  __shared__ float sW1[512], sb1[32], sW2[512], sb2[16];
  __shared__ float fs[4][12], x0s[4][64];
  int tid = threadIdx.x;
  if (tid == 0) cnt = 0;
  __syncthreads();
  atomicAdd(&cnt, voteSlice((const u16*)feats, tid, 256));
  __syncthreads();
  bool isbf = (cnt <= 100);
  int bid = blockIdx.x;

  if (bid < 8) {
    int g = bid * 256 + tid;
    int l = g >> 10, bin = g & 1023;
    for (int k = tid; k < 512; k += 256) {
      sW1[k] = ldraw(rW1, l * 512 + k, isbf);
      sW2[k] = ldraw(rW2, l * 512 + k, isbf);
    }
    if (tid < 32) sb1[tid] = ldraw(rb1, l * 32 + tid, isbf);
    if (tid < 16) sb2[tid] = ldraw(rb2, l * 16 + tid, isbf);
    __syncthreads();
    float w[2][16];
#pragma unroll
    for (int t = 0; t < 2; ++t) {
      float d = (float)(bin + t) * 0.01f;
      float rbf[16];
#pragma unroll
      for (int r = 0; r < 16; ++r) {
        float x = d - (10.0f / 15.0f) * (float)r;
        rbf[r] = __expf(-x * x * 1.28f);
      }
#pragma unroll
      for (int o = 0; o < 16; ++o) w[t][o] = sb2[o];
      for (int k = 0; k < 32; ++k) {
        float acc = sb1[k];
#pragma unroll
        for (int r = 0; r < 16; ++r) acc += rbf[r] * sW1[r * 32 + k];
        acc = fmaxf(acc, 0.f);
#pragma unroll
        for (int o = 0; o < 16; ++o) w[t][o] += acc * sW2[k * 16 + o];
      }
    }
#pragma unroll
    for (int o = 0; o < 16; ++o)
      tab[l * 16384 + bin * 16 + o] = make_float2(w[0][o], w[1][o]);
  } else {
    int u = bid - 8;
    if (isbf)
      proj0_body<u16>(fs, x0s, (const u16*)feats, (const u16*)W_emb, (const u16*)b_emb,
                      (const u16*)g0, (const u16*)b0, (const u16*)Wq0, (const u16*)Wk0,
                      (const u16*)Wv0, f0, q0, k0, v0, u, tid);
    else
      proj0_body<float>(fs, x0s, (const float*)feats, (const float*)W_emb,
                        (const float*)b_emb, (const float*)g0, (const float*)b0,
                        (const float*)Wq0, (const float*)Wk0, (const float*)Wv0, f0, q0,
                        k0, v0, u, tid);
  }
}

// ================= attention (validated, unchanged from r13) =================
template <int HASF1>
__global__ void __launch_bounds__(256, 4) k_attn(
    const void* featsraw, const void* coords, const float2* __restrict__ tab,
    const u16* __restrict__ q0, const u16* __restrict__ k0, const u16* __restrict__ v0,
    const u16* __restrict__ q1, const u16* __restrict__ k1, const u16* __restrict__ v1,
    float* __restrict__ out0, float* __restrict__ out1) {
  __shared__ union {
    u16 ks[128][64];
    u16 A16[64][128];
  } U;
  __shared__ unsigned int S01[8][128];
  __shared__ u16 Bt[64][128];
  __shared__ float cs[3][128];
  __shared__ int cnt;

  int tid = threadIdx.x;
  if (tid == 0) cnt = 0;
  __syncthreads();
  atomicAdd(&cnt, voteSlice((const u16*)featsraw, tid, 256));
  __syncthreads();
  bool isbf = (cnt <= 100);

  int bid = blockIdx.x;
  int bh = bid & 63, it = bid >> 6;
  int h = bh & 3, b = bh >> 2;
  int ibase = it * 8;
  size_t rowbase = (size_t)bh * 128;
  int lane = tid & 63, waveid = tid >> 6;
  int ln = lane & 15, lg = lane >> 4;

  short8 P0f = {0, 0, 0, 0, 0, 0, 0, 0};
  short8 P1f = {0, 0, 0, 0, 0, 0, 0, 0};
  short8 P2f = {0, 0, 0, 0, 0, 0, 0, 0};
  if (ln < 8) {
    int i = ibase + ln;
    if (HASF1) {
      const u16* q1p = q1 + (rowbase + i) * 48;
      P0f = *(const short8*)&q1p[lg * 8];
      if (lg < 2) P1f = *(const short8*)&q1p[32 + lg * 8];
    }
    if (lg >= 2) {
      const u16* q0p = q0 + (rowbase + i) * 16;
      P2f = *(const short8*)&q0p[(lg - 2) * 8];
    }
  }

  if (HASF1) {
    for (int e = tid; e < 2048; e += 256) {
      int j = e >> 4, t0 = (e & 15) * 4;
      ushort4 pk;
      if (t0 < 48) pk = *(const ushort4*)&k1[(rowbase + j) * 48 + t0];
      else pk = *(const ushort4*)&k0[(rowbase + j) * 16 + (t0 - 48)];
      int g = t0 >> 3;
      *(ushort4*)&U.ks[j][((g ^ (j & 7)) << 3) | (t0 & 7)] = pk;
    }
  } else {
    for (int e = tid; e < 1024; e += 256) {
      int j = e >> 3, t0 = 32 + (e & 7) * 4;
      ushort4 pk = {0, 0, 0, 0};
      if (t0 >= 48) pk = *(const ushort4*)&k0[(rowbase + j) * 16 + (t0 - 48)];
      int g = t0 >> 3;
      *(ushort4*)&U.ks[j][((g ^ (j & 7)) << 3) | (t0 & 7)] = pk;
    }
  }
  for (int e = tid; e < 512; e += 256) {
    int j = e >> 2, q = e & 3;
    ushort4 f = *(const ushort4*)&v0[(rowbase + j) * 16 + q * 4];
    int jhi = j >> 3, jl = j & 7;
#pragma unroll
    for (int i2 = 0; i2 < 4; ++i2) {
      int d = q * 4 + i2;
      int sl = (jhi ^ d) << 3;
      u16 fv = (i2 == 0) ? f.x : (i2 == 1) ? f.y : (i2 == 2) ? f.z : f.w;
      Bt[d][sl | jl] = fv;
      if (!HASF1) {
        Bt[16 + d][sl | jl] = 0;
        Bt[32 + d][sl | jl] = 0;
        Bt[48 + d][sl | jl] = 0;
      }
    }
  }
  if (HASF1) {
    for (int e = tid; e < 1536; e += 256) {
      int j = e / 12, q = e - j * 12;
      ushort4 f = *(const ushort4*)&v1[(rowbase + j) * 48 + q * 4];
      int jhi = j >> 3, jl = j & 7;
#pragma unroll
      for (int i2 = 0; i2 < 4; ++i2) {
        int flat = q * 4 + i2;
        int d = flat / 3, vv = flat - d * 3;
        int sl = (jhi ^ d) << 3;
        u16 fv = (i2 == 0) ? f.x : (i2 == 1) ? f.y : (i2 == 2) ? f.z : f.w;
        Bt[(vv + 1) * 16 + d][sl | jl] = fv;
      }
    }
  }
  if (tid < 128) {
    cs[0][tid] = ldraw(coords, ((int)b * 128 + tid) * 3 + 0, isbf);
    cs[1][tid] = ldraw(coords, ((int)b * 128 + tid) * 3 + 1, isbf);
    cs[2][tid] = ldraw(coords, ((int)b * 128 + tid) * 3 + 2, isbf);
  }
  __syncthreads();  // bar1

#pragma unroll
  for (int q = 0; q < 2; ++q) {
    int j = (waveid * 2 + q) * 16 + ln;
    int swz = j & 7;
    short8 bk1 = *(const short8*)&U.ks[j][(((4 + lg) ^ swz) << 3)];
    float4v a0 = {0.f, 0.f, 0.f, 0.f};
    a0 = __builtin_amdgcn_mfma_f32_16x16x32_bf16(P2f, bk1, a0, 0, 0, 0);
    float4v a1 = {0.f, 0.f, 0.f, 0.f};
    if (HASF1) {
      short8 bk0 = *(const short8*)&U.ks[j][((lg ^ swz) << 3)];
      a1 = __builtin_amdgcn_mfma_f32_16x16x32_bf16(P0f, bk0, a1, 0, 0, 0);
      a1 = __builtin_amdgcn_mfma_f32_16x16x32_bf16(P1f, bk1, a1, 0, 0, 0);
    }
    if (lg < 2) {
#pragma unroll
      for (int r = 0; r < 4; ++r) {
        unsigned int pk =
            (unsigned int)f2bu(a0[r]) | ((unsigned int)f2bu(a1[r]) << 16);
        S01[lg * 4 + r][j] = pk;
      }
    }
  }
  __syncthreads();  // bar2

  {
    int row = tid >> 5, jg = tid & 31;
    int i = ibase + row;
    float cix = cs[0][i], ciy = cs[1][i], ciz = cs[2][i];
    uint4 sv = *(const uint4*)&S01[row][jg * 4];
    float e4[4], w4[4][4], yv[4][3];
    int nmmask = 0;
    float mx = -3e38f;
#pragma unroll
    for (int jj = 0; jj < 4; ++jj) {
      int j = jg * 4 + jj;
      float rx = cs[0][j] - cix;
      float ry = cs[1][j] - ciy;
      float rz = cs[2][j] - ciz;
      float dd = sqrtf(rx * rx + ry * ry + rz * rz + 1e-8f);
      float inv = 1.f / dd;
      yv[jj][0] = rx * inv; yv[jj][1] = ry * inv; yv[jj][2] = rz * inv;
      float tt = fminf(dd, 10.229f) * 100.f;
      int i0 = (int)tt;
      float fr = tt - (float)i0;
      const float2* Tp = tab + (i0 << 4) + h;
      float2 t0 = Tp[0], t1 = Tp[4], t2 = Tp[8], t3 = Tp[12];
      w4[jj][0] = t0.x + fr * (t0.y - t0.x);
      w4[jj][1] = t1.x + fr * (t1.y - t1.x);
      w4[jj][2] = t2.x + fr * (t2.y - t2.x);
      w4[jj][3] = t3.x + fr * (t3.y - t3.x);
      unsigned int sw = (jj == 0) ? sv.x : (jj == 1) ? sv.y : (jj == 2) ? sv.z : sv.w;
      float s0j = bits2f((u16)(sw & 0xffffu));
      float s1j = bits2f((u16)(sw >> 16));
      float sim = (s0j * w4[jj][0] + (HASF1 ? s1j * w4[jj][3] : 0.f)) * 0.25f;
      bool nm = (dd <= 10.0f) && (j != i);
      if (nm) nmmask |= (1 << jj);
      sim = nm ? sim : -1e9f;
      e4[jj] = sim;
      mx = fmaxf(mx, sim);
    }
#pragma unroll
    for (int m = 1; m < 32; m <<= 1) mx = fmaxf(mx, __shfl_xor(mx, m, 64));
    float ssum = 0.f;
#pragma unroll
    for (int jj = 0; jj < 4; ++jj) {
      e4[jj] = __expf(e4[jj] - mx);
      ssum += e4[jj];
    }
#pragma unroll
    for (int m = 1; m < 32; m <<= 1) ssum += __shfl_xor(ssum, m, 64);
    float rinv = 1.f / ssum;
    float aj[4];
#pragma unroll
    for (int jj = 0; jj < 4; ++jj)
      aj[jj] = ((nmmask >> jj) & 1) ? e4[jj] * rinv : 0.f;
#pragma unroll
    for (int s = 0; s < 8; ++s) {
      u16 t4[4];
#pragma unroll
      for (int jj = 0; jj < 4; ++jj) {
        float v;
        if (s == 0) v = aj[jj] * w4[jj][0];
        else if (s < 4) v = aj[jj] * w4[jj][2] * yv[jj][s - 1];
        else if (s < 7) v = aj[jj] * w4[jj][1] * yv[jj][s - 4];
        else v = aj[jj] * w4[jj][3];
        t4[jj] = f2bu(v);
      }
      ushort4 pk = {t4[0], t4[1], t4[2], t4[3]};
      int arow = row * 8 + s;
      int g = jg >> 1;
      *(ushort4*)&U.A16[arow][(((g ^ (arow & 15)) << 3) | ((jg & 1) * 4))] = pk;
    }
  }
  __syncthreads();  // bar3

  float4v acc[4];
#pragma unroll
  for (int nt = 0; nt < 4; ++nt) acc[nt] = (float4v){0.f, 0.f, 0.f, 0.f};
  int m = waveid * 16 + ln;
#pragma unroll
  for (int kst = 0; kst < 4; ++kst) {
    int gk = kst * 4 + lg;
    short8 af = *(const short8*)&U.A16[m][((gk ^ ln) << 3)];
#pragma unroll
    for (int nt = 0; nt < 4; ++nt) {
      short8 bf = *(const short8*)&Bt[nt * 16 + ln][((gk ^ ln) << 3)];
      acc[nt] = __builtin_amdgcn_mfma_f32_16x16x32_bf16(af, bf, acc[nt], 0, 0, 0);
    }
  }
  {
    int qr = waveid * 2 + (lg >> 1);
    size_t orow = rowbase + ibase + qr;
    if ((lg & 1) == 0) {
      out0[orow * 16 + ln] = acc[0][0] + acc[1][1] + acc[2][2] + acc[3][3];
    } else {
#pragma unroll
      for (int vv = 0; vv < 3; ++vv)
        out1[orow * 48 + ln * 3 + vv] = acc[0][vv] + acc[1 + vv][3];
    }
  }
}

// ================= nodeM: MFMA post+FF(+proj1), 16 rows/block =================
struct NodeMS {
  u16 wL[16384];       // 32K weight scratch (transposed, swizzled)
  u16 aA[4096];        // [64 rows][64] bf16 A-matrices
  u16 hbA[4096];       // [16][256] bf16 hidden A-matrix
  float Cb[64][68];    // C buffer
  float f1gL[3072];    // [16][192] f32 gated f1
  float sFb[256];      // fb1
};

template <int LAST, typename WT>
__device__ void nodeM_body(NodeMS& S, int bid, const WT* Wo0, const WT* bo0,
                           const WT* Wo1, const WT* gn, const WT* bn, const WT* g2,
                           const WT* b2w, const WT* F1, const WT* fb1, const WT* F2,
                           const WT* fb2, const WT* Wf1, const WT* g0n, const WT* b0n,
                           const WT* Wq0n, const WT* Wk0n, const WT* Wv0n,
                           const WT* Wq1n, const WT* Wk1n, const WT* Wv1n,
                           const float* __restrict__ out0, const float* __restrict__ out1,
                           float* __restrict__ f0, u16* __restrict__ q0,
                           u16* __restrict__ k0, u16* __restrict__ v0,
                           u16* __restrict__ q1, u16* __restrict__ k1,
                           u16* __restrict__ v1, int tid) {
  int R0 = bid * 16;
  int b = R0 >> 7;
  int n0 = R0 & 127;
  int lane = tid & 63, waveid = tid >> 6;
  int ln = lane & 15, lg = lane >> 4;

  // ---- S0: stage o0 (+o1 stacks) into aA; Wo0T (+Wo1T) into wL ----
  for (int e = tid; e < 1024; e += 256) {
    int r = e >> 6, t = e & 63;
    float v = out0[((size_t)((b * 4 + (t >> 4)) * 128 + n0 + r)) * 16 + (t & 15)];
    S.aA[off64(r, t)] = f2bu(v);
  }
  if (!LAST) {
    for (int e = tid; e < 3072; e += 256) {
      int vv = e >> 10, rem = e & 1023;
      int r = rem >> 6, t = rem & 63;
      float v =
          out1[((size_t)((b * 4 + (t >> 4)) * 128 + n0 + r)) * 48 + (t & 15) * 3 + vv];
      S.aA[off64(16 + vv * 16 + r, t)] = f2bu(v);
    }
  }
  for (int e = tid; e < 4096; e += 256) {
    int k = e >> 6, nn = e & 63;
    S.wL[off64(nn, k)] = f2bu(ldw(Wo0, k * 64 + nn));
    if (!LAST) S.wL[4096 + off64(nn, k)] = f2bu(ldw(Wo1, k * 64 + nn));
  }
  __syncthreads();

  // ---- G1: C[64x64] = {o0@Wo0T; o1x/y/z@Wo1T} ----
  {
    float4v acc[4];
#pragma unroll
    for (int mt = 0; mt < 4; ++mt) acc[mt] = (float4v){0.f, 0.f, 0.f, 0.f};
#pragma unroll
    for (int mt = 0; mt < (LAST ? 1 : 4); ++mt) {
#pragma unroll
      for (int kt = 0; kt < 2; ++kt) {
        int oct = (kt * 4 + lg) * 8;
        short8 af = *(const short8*)&S.aA[off64(mt * 16 + ln, oct)];
        const u16* wb = (mt == 0) ? S.wL : (S.wL + 4096);
        short8 bf = *(const short8*)&wb[off64(waveid * 16 + ln, oct)];
        acc[mt] = __builtin_amdgcn_mfma_f32_16x16x32_bf16(af, bf, acc[mt], 0, 0, 0);
      }
    }
#pragma unroll
    for (int mt = 0; mt < (LAST ? 1 : 4); ++mt)
#pragma unroll
      for (int r = 0; r < 4; ++r)
        S.Cb[mt * 16 + lg * 4 + r][waveid * 16 + ln] = acc[mt][r];
  }
  __syncthreads();

  // ---- E1: residual + gate + LN; xn->aA[0..15], f1g->aA[16..63]+f1gL ----
  float rsv[4];
#pragma unroll
  for (int p = 0; p < 4; ++p) {
    int r = p * 4 + waveid;
    int c = lane;
    float a0 = S.Cb[r][c] + ldw(bo0, c);
    float f0p = f0[(size_t)(R0 + r) * 64 + c] + a0;
    rsv[p] = f0p;
    if (!LAST) {
      float fx = S.Cb[16 + r][c], fy = S.Cb[32 + r][c], fz = S.Cb[48 + r][c];
      float n1 = sqrtf(fx * fx + fy * fy + fz * fz + 1e-8f);
      float gate = fmaxf(n1 * ldw(gn, c) + ldw(bn, c), 0.f);
      float sc = gate / n1;
      float gx = fx * sc, gy = fy * sc, gz = fz * sc;
      S.f1gL[r * 192 + c * 3 + 0] = gx;
      S.f1gL[r * 192 + c * 3 + 1] = gy;
      S.f1gL[r * 192 + c * 3 + 2] = gz;
      S.aA[off64(16 + r, c)] = f2bu(gx);
      S.aA[off64(32 + r, c)] = f2bu(gy);
      S.aA[off64(48 + r, c)] = f2bu(gz);
    }
    float mu = waveSum64(f0p) * (1.f / 64.f);
    float dv = f0p - mu;
    float var = waveSum64(dv * dv) * (1.f / 64.f);
    float xn = dv * rsqrtf(var + 1e-5f) * ldw(g2, c) + ldw(b2w, c);
    S.aA[off64(r, c)] = f2bu(xn);
  }
  __syncthreads();

  // ---- S2: F1T [256n][64k] -> wL; fb1 -> sFb ----
  for (int e = tid; e < 16384; e += 256) {
    int k = e >> 8, nn = e & 255;
    S.wL[off64(nn, k)] = f2bu(ldw(F1, k * 256 + nn));
  }
  if (tid < 256) S.sFb[tid] = ldw(fb1, tid);
  __syncthreads();

  // ---- G2: hb[16x256] = relu(xn@F1T + fb1) -> hbA ----
  {
    float4v a2[4];
#pragma unroll
    for (int q = 0; q < 4; ++q) a2[q] = (float4v){0.f, 0.f, 0.f, 0.f};
#pragma unroll
    for (int q = 0; q < 4; ++q) {
#pragma unroll
      for (int kt = 0; kt < 2; ++kt) {
        int oct = (kt * 4 + lg) * 8;
        short8 af = *(const short8*)&S.aA[off64(ln, oct)];
        int nn = (waveid * 4 + q) * 16 + ln;
        short8 bf = *(const short8*)&S.wL[off64(nn, oct)];
        a2[q] = __builtin_amdgcn_mfma_f32_16x16x32_bf16(af, bf, a2[q], 0, 0, 0);
      }
    }
#pragma unroll
    for (int q = 0; q < 4; ++q) {
      int nn = (waveid * 4 + q) * 16 + ln;
#pragma unroll
      for (int r = 0; r < 4; ++r) {
        int m = lg * 4 + r;
        float v = fmaxf(a2[q][r] + S.sFb[nn], 0.f);
        S.hbA[off256(m, nn)] = f2bu(v);
      }
    }
  }
  __syncthreads();

  // ---- S3: F2T [64n][256k] -> wL ----
  for (int e = tid; e < 16384; e += 256) {
    int k = e >> 6, nn = e & 63;
    S.wL[off256(nn, k)] = f2bu(ldw(F2, k * 64 + nn));
  }
  __syncthreads();

  // ---- G3: C[16x64] = hb@F2T -> Cb rows 0-15 ----
  {
    float4v a3 = {0.f, 0.f, 0.f, 0.f};
#pragma unroll
    for (int kt = 0; kt < 8; ++kt) {
      int oct = (kt * 4 + lg) * 8;
      short8 af = *(const short8*)&S.hbA[off256(ln, oct)];
      short8 bf = *(const short8*)&S.wL[off256(waveid * 16 + ln, oct)];
      a3 = __builtin_amdgcn_mfma_f32_16x16x32_bf16(af, bf, a3, 0, 0, 0);
    }
#pragma unroll
    for (int r = 0; r < 4; ++r) S.Cb[lg * 4 + r][waveid * 16 + ln] = a3[r];
  }
  __syncthreads();

  if (!LAST) {
    // ---- S4: Wf1T -> wL ----
    for (int e = tid; e < 4096; e += 256) {
      int k = e >> 6, nn = e & 63;
      S.wL[off64(nn, k)] = f2bu(ldw(Wf1, k * 64 + nn));
    }
    __syncthreads();
    // ---- G4: C[48x64] = f1g@Wf1T -> Cb rows 16-63 ----
    {
      float4v aw[3];
#pragma unroll
      for (int mt = 0; mt < 3; ++mt) aw[mt] = (float4v){0.f, 0.f, 0.f, 0.f};
#pragma unroll
      for (int mt = 0; mt < 3; ++mt) {
#pragma unroll
        for (int kt = 0; kt < 2; ++kt) {
          int oct = (kt * 4 + lg) * 8;
          short8 af = *(const short8*)&S.aA[off64((mt + 1) * 16 + ln, oct)];
          short8 bf = *(const short8*)&S.wL[off64(waveid * 16 + ln, oct)];
          aw[mt] = __builtin_amdgcn_mfma_f32_16x16x32_bf16(af, bf, aw[mt], 0, 0, 0);
        }
      }
#pragma unroll
      for (int mt = 0; mt < 3; ++mt)
#pragma unroll
        for (int r = 0; r < 4; ++r)
          S.Cb[(mt + 1) * 16 + lg * 4 + r][waveid * 16 + ln] = aw[mt][r];
    }
    __syncthreads();
  }

  // ---- E3: f0 out; (!LAST) x0s & f1n -> aA ----
#pragma unroll
  for (int p = 0; p < 4; ++p) {
    int r = p * 4 + waveid;
    int c = lane;
    float f0n = rsv[p] + ldw(fb2, c) + S.Cb[r][c];
    f0[(size_t)(R0 + r) * 64 + c] = f0n;
    if (!LAST) {
      float mu2 = waveSum64(f0n) * (1.f / 64.f);
      float dv2 = f0n - mu2;
      float var2 = waveSum64(dv2 * dv2) * (1.f / 64.f);
      float x0 = dv2 * rsqrtf(var2 + 1e-5f) * ldw(g0n, c) + ldw(b0n, c);
      S.aA[off64(r, c)] = f2bu(x0);
#pragma unroll
      for (int vv = 0; vv < 3; ++vv) {
        float f1n = S.f1gL[r * 192 + c * 3 + vv] + S.Cb[(vv + 1) * 16 + r][c];
        S.aA[off64((vv + 1) * 16 + r, c)] = f2bu(f1n);
      }
    }
  }
  if (LAST) return;
  __syncthreads();

  // ---- S5a: Wq0T,Wk0T,Wv0T,Wq1T -> wL ----
  for (int e = tid; e < 4096; e += 256) {
    int k = e >> 6, nn = e & 63;
    S.wL[off64(nn, k)] = f2bu(ldw(Wq0n, k * 64 + nn));
    S.wL[4096 + off64(nn, k)] = f2bu(ldw(Wk0n, k * 64 + nn));
    S.wL[8192 + off64(nn, k)] = f2bu(ldw(Wv0n, k * 64 + nn));
    S.wL[12288 + off64(nn, k)] = f2bu(ldw(Wq1n, k * 64 + nn));
  }
  __syncthreads();
  {
    float4v aq = {0, 0, 0, 0}, ak = {0, 0, 0, 0}, av = {0, 0, 0, 0};
    float4v aq1[3];
#pragma unroll
    for (int mt = 0; mt < 3; ++mt) aq1[mt] = (float4v){0.f, 0.f, 0.f, 0.f};
#pragma unroll
    for (int kt = 0; kt < 2; ++kt) {
      int oct = (kt * 4 + lg) * 8;
      short8 af0 = *(const short8*)&S.aA[off64(ln, oct)];
      int nn = waveid * 16 + ln;
      short8 bq = *(const short8*)&S.wL[off64(nn, oct)];
      short8 bk = *(const short8*)&S.wL[4096 + off64(nn, oct)];
      short8 bv = *(const short8*)&S.wL[8192 + off64(nn, oct)];
      aq = __builtin_amdgcn_mfma_f32_16x16x32_bf16(af0, bq, aq, 0, 0, 0);
      ak = __builtin_amdgcn_mfma_f32_16x16x32_bf16(af0, bk, ak, 0, 0, 0);
      av = __builtin_amdgcn_mfma_f32_16x16x32_bf16(af0, bv, av, 0, 0, 0);
#pragma unroll
      for (int mt = 0; mt < 3; ++mt) {
        short8 af1 = *(const short8*)&S.aA[off64((mt + 1) * 16 + ln, oct)];
        short8 bw = *(const short8*)&S.wL[12288 + off64(nn, oct)];
        aq1[mt] = __builtin_amdgcn_mfma_f32_16x16x32_bf16(af1, bw, aq1[mt], 0, 0, 0);
      }
    }
    // writes: c = waveid*16+ln -> h = waveid, d = ln
#pragma unroll
    for (int r = 0; r < 4; ++r) {
      int R = R0 + lg * 4 + r;
      size_t rb = (size_t)((b * 4 + waveid) * 128 + (R & 127));
      q0[rb * 16 + ln] = f2bu(aq[r]);
      k0[rb * 16 + ln] = f2bu(ak[r]);
      v0[rb * 16 + ln] = f2bu(av[r]);
#pragma unroll
      for (int mt = 0; mt < 3; ++mt) q1[rb * 48 + ln * 3 + mt] = f2bu(aq1[mt][r]);
    }
  }
  __syncthreads();

  // ---- S5b: Wk1T, Wv1T -> wL ----
  for (int e = tid; e < 4096; e += 256) {
    int k = e >> 6, nn = e & 63;
    S.wL[off64(nn, k)] = f2bu(ldw(Wk1n, k * 64 + nn));
    S.wL[4096 + off64(nn, k)] = f2bu(ldw(Wv1n, k * 64 + nn));
  }
  __syncthreads();
  {
    float4v ak1[3], av1[3];
#pragma unroll
    for (int mt = 0; mt < 3; ++mt) {
      ak1[mt] = (float4v){0.f, 0.f, 0.f, 0.f};
      av1[mt] = (float4v){0.f, 0.f, 0.f, 0.f};
    }
#pragma unroll
    for (int kt = 0; kt < 2; ++kt) {
      int oct = (kt * 4 + lg) * 8;
      int nn = waveid * 16 + ln;
      short8 bk = *(const short8*)&S.wL[off64(nn, oct)];
      short8 bv = *(const short8*)&S.wL[4096 + off64(nn, oct)];
#pragma unroll
      for (int mt = 0; mt < 3; ++mt) {
        short8 af1 = *(const short8*)&S.aA[off64((mt + 1) * 16 + ln, oct)];
        ak1[mt] = __builtin_amdgcn_mfma_f32_16x16x32_bf16(af1, bk, ak1[mt], 0, 0, 0);
        av1[mt] = __builtin_amdgcn_mfma_f32_16x16x32_bf16(af1, bv, av1[mt], 0, 0, 0);
      }
    }
#pragma unroll
    for (int r = 0; r < 4; ++r) {
      int R = R0 + lg * 4 + r;
      size_t rb = (size_t)((b * 4 + waveid) * 128 + (R & 127));
#pragma unroll
      for (int mt = 0; mt < 3; ++mt) {
        k1[rb * 48 + ln * 3 + mt] = f2bu(ak1[mt][r]);
        v1[rb * 48 + ln * 3 + mt] = f2bu(av1[mt][r]);
      }
    }
  }
}

template <int LAST>
__global__ void __launch_bounds__(256) k_nodeM(
    const void* featsraw, const void* Wq0, const void* Wk0, const void* Wv0,
    const void* Wq1, const void* Wk1, const void* Wv1, const void* Wo0,
    const void* bo0, const void* Wo1, const void* g0, const void* b0, const void* gn,
    const void* bn, const void* g2, const void* b2w, const void* F1, const void* fb1,
    const void* F2, const void* fb2, const void* Wf1, const float* __restrict__ out0,
    const float* __restrict__ out1, float* __restrict__ f0, u16* __restrict__ q0,
    u16* __restrict__ k0, u16* __restrict__ v0, u16* __restrict__ q1,
    u16* __restrict__ k1, u16* __restrict__ v1, int l) {
  __shared__ NodeMS S;
  __shared__ int cnt;
  int tid = threadIdx.x;
  if (tid == 0) cnt = 0;
  __syncthreads();
  atomicAdd(&cnt, voteSlice((const u16*)featsraw, tid, 256));
  __syncthreads();
  bool isbf = (cnt <= 100);
  int l2 = l + 1;
  if (isbf) {
    nodeM_body<LAST, u16>(
        S, blockIdx.x, (const u16*)Wo0 + l * 4096, (const u16*)bo0 + l * 64,
        (const u16*)Wo1 + l * 4096, (const u16*)gn + l * 64, (const u16*)bn + l * 64,
        (const u16*)g2 + l * 64, (const u16*)b2w + l * 64, (const u16*)F1 + l * 16384,
        (const u16*)fb1 + l * 256, (const u16*)F2 + l * 16384, (const u16*)fb2 + l * 64,
        (const u16*)Wf1 + l * 4096, (const u16*)g0 + l2 * 64, (const u16*)b0 + l2 * 64,
        (const u16*)Wq0 + l2 * 4096, (const u16*)Wk0 + l2 * 4096,
        (const u16*)Wv0 + l2 * 4096, (const u16*)Wq1 + l2 * 4096,
        (const u16*)Wk1 + l2 * 4096, (const u16*)Wv1 + l2 * 4096, out0, out1, f0, q0,
        k0, v0, q1, k1, v1, tid);
  } else {
    nodeM_body<LAST, float>(
        S, blockIdx.x, (const float*)Wo0 + l * 4096, (const float*)bo0 + l * 64,
        (const float*)Wo1 + l * 4096, (const float*)gn + l * 64,
        (const float*)bn + l * 64, (const float*)g2 + l * 64,
        (const float*)b2w + l * 64, (const float*)F1 + l * 16384,
        (const float*)fb1 + l * 256, (const float*)F2 + l * 16384,
        (const float*)fb2 + l * 64, (const float*)Wf1 + l * 4096,
        (const float*)g0 + l2 * 64, (const float*)b0 + l2 * 64,
        (const float*)Wq0 + l2 * 4096, (const float*)Wk0 + l2 * 4096,
        (const float*)Wv0 + l2 * 4096, (const float*)Wq1 + l2 * 4096,
        (const float*)Wk1 + l2 * 4096, (const float*)Wv1 + l2 * 4096, out0, out1, f0,
        q0, k0, v0, q1, k1, v1, tid);
  }
}

// ================= final =================
__global__ void k_final(const void* featsraw, const float* __restrict__ f0,
                        const void* Wout, const void* bout, void* __restrict__ out) {
  int b = blockIdx.x;
  int c = threadIdx.x;  // 0..63
  __shared__ float ps[64];
  int insane = voteSlice((const u16*)featsraw, c, 64);
  float cntf = waveSum64((float)insane);
  bool isbf = (cntf <= 100.f);
  float s = 0;
  for (int n = 0; n < 128; n++) s += f0[((size_t)b * 128 + n) * 64 + c];
  ps[c] = s * (1.f / 128.f);
  __syncthreads();
  if (c < 19) {
    float a = ldraw(bout, c, isbf);
    for (int k = 0; k < 64; k++) a += ps[k] * ldraw(Wout, k * 19 + c, isbf);
    if (isbf) ((bf16*)out)[b * 19 + c] = __float2bfloat16(a);
    else ((float*)out)[b * 19 + c] = a;
  }
}

extern "C" void kernel_launch(void* const* d_in, const int* in_sizes, int n_in, void* d_out,
                              int out_size, void* d_ws, size_t ws_size, hipStream_t stream) {
  (void)in_sizes; (void)n_in; (void)out_size; (void)ws_size;

  const void* feats = d_in[0];
  const void* coords = d_in[1];
  const void* W_emb = d_in[2];
  const void* b_emb = d_in[3];
  const void* Wq0 = d_in[4];
  const void* Wk0 = d_in[5];
  const void* Wv0 = d_in[6];
  const void* Wq1 = d_in[7];
  const void* Wk1 = d_in[8];
  const void* Wv1 = d_in[9];
  const void* rW1 = d_in[10];
  const void* rb1 = d_in[11];
  const void* rW2 = d_in[12];
  const void* rb2 = d_in[13];
  const void* Wo0 = d_in[14];
  const void* bo0 = d_in[15];
  const void* Wo1 = d_in[16];
  const void* g0 = d_in[17];
  const void* b0 = d_in[18];
  const void* gn = d_in[19];
  const void* bn = d_in[20];
  const void* g2 = d_in[21];
  const void* b2w = d_in[22];
  const void* F1 = d_in[23];
  const void* fb1 = d_in[24];
  const void* F2 = d_in[25];
  const void* fb2 = d_in[26];
  const void* Wf1 = d_in[27];
  const void* Wout = d_in[28];
  const void* bout = d_in[29];

  float* fp = (float*)d_ws;
  float* f0 = fp; fp += 131072;
  float* out0 = fp; fp += 131072;
  float* out1 = fp; fp += 393216;
  float2* tab2 = (float2*)fp; fp += 65536;
  u16* up = (u16*)fp;
  u16* q0u = up; up += 131072;
  u16* k0u = up; up += 131072;
  u16* v0u = up; up += 131072;
  u16* q1u = up; up += 393216;
  u16* k1u = up; up += 393216;
  u16* v1u = up; up += 393216;

  k_tabproj0<<<520, 256, 0, stream>>>(feats, rW1, rb1, rW2, rb2, W_emb, b_emb, g0, b0,
                                      Wq0, Wk0, Wv0, tab2, f0, q0u, k0u, v0u);
  k_attn<0><<<1024, 256, 0, stream>>>(feats, coords, tab2, q0u, k0u, v0u, q1u, k1u, v1u,
                                      out0, out1);
  k_nodeM<0><<<128, 256, 0, stream>>>(feats, Wq0, Wk0, Wv0, Wq1, Wk1, Wv1, Wo0, bo0, Wo1,
                                      g0, b0, gn, bn, g2, b2w, F1, fb1, F2, fb2, Wf1,
                                      out0, out1, f0, q0u, k0u, v0u, q1u, k1u, v1u, 0);
  k_attn<1><<<1024, 256, 0, stream>>>(feats, coords, tab2 + 16384, q0u, k0u, v0u, q1u,
                                      k1u, v1u, out0, out1);
  k_nodeM<1><<<128, 256, 0, stream>>>(feats, Wq0, Wk0, Wv0, Wq1, Wk1, Wv1, Wo0, bo0, Wo1,
                                      g0, b0, gn, bn, g2, b2w, F1, fb1, F2, fb2, Wf1,
                                      out0, out1, f0, q0u, k0u, v0u, q1u, k1u, v1u, 1);
  k_final<<<16, 64, 0, stream>>>(feats, f0, Wout, bout, d_out);
}